// Round 1
// baseline (2151.735 us; speedup 1.0000x reference)
//
#include <hip/hip_runtime.h>
#include <hip/hip_bf16.h>
#include <math.h>

// Problem constants (fixed by the reference)
#define DIMN   1024
#define HEADS  16
#define DHEAD  64
#define BQKV   3072
#define BATCH  4
#define SEQ    1024
#define NROWS  (BATCH * SEQ)     // 4096
#define ATT_SCALE 0.125f         // 1/sqrt(64)
#define LN_EPS 1e-5f

// ---------------------------------------------------------------------------
// Kernel 1: svd_adapt[d] = sigma * sum_r U[d,r] * (sum_j V[r,j])
// ---------------------------------------------------------------------------
__global__ __launch_bounds__(1024) void svd_kernel(
    const float* __restrict__ U, const float* __restrict__ V,
    const float* __restrict__ sigma_p, float* __restrict__ svd)
{
    __shared__ float part[16][4];
    __shared__ float vsum[4];
    const int tid = threadIdx.x;          // 0..1023
    float v0 = V[0 * DIMN + tid];
    float v1 = V[1 * DIMN + tid];
    float v2 = V[2 * DIMN + tid];
    float v3 = V[3 * DIMN + tid];
    #pragma unroll
    for (int off = 32; off > 0; off >>= 1) {
        v0 += __shfl_down(v0, off);
        v1 += __shfl_down(v1, off);
        v2 += __shfl_down(v2, off);
        v3 += __shfl_down(v3, off);
    }
    const int lane = tid & 63, w = tid >> 6;
    if (lane == 0) { part[w][0] = v0; part[w][1] = v1; part[w][2] = v2; part[w][3] = v3; }
    __syncthreads();
    if (tid < 4) {
        float s = 0.f;
        #pragma unroll
        for (int i = 0; i < 16; ++i) s += part[i][tid];
        vsum[tid] = s;
    }
    __syncthreads();
    const float sg = sigma_p[0];
    float acc = U[tid * 4 + 0] * vsum[0] + U[tid * 4 + 1] * vsum[1]
              + U[tid * 4 + 2] * vsum[2] + U[tid * 4 + 3] * vsum[3];
    svd[tid] = sg * acc;
}

// ---------------------------------------------------------------------------
// Kernel 2: generic C = (A (+adapt)) @ W^T (+bias)
//   A: [M,K] row-major (lda), W: [N,K] row-major (ldw), C: [M,N] (ldc)
//   M = gridDim.y*128, N = gridDim.x*128. K % 16 == 0, M,N % 128 == 0.
// Classic 128x128x16 SGEMM, 256 threads, 8x8 micro-tile per thread.
// ---------------------------------------------------------------------------
#define BM 128
#define BN 128
#define BK 16

__global__ __launch_bounds__(256) void gemm_nt(
    const float* __restrict__ A, int lda,
    const float* __restrict__ adapt,          // nullable, length K, added to A cols
    const float* __restrict__ W, int ldw,
    const float* __restrict__ bias,           // nullable, length N
    float* __restrict__ C, int ldc, int K)
{
    __shared__ __align__(16) float As[BK][BM + 4];
    __shared__ __align__(16) float Bs[BK][BN + 4];
    const int tid = threadIdx.x;
    const int tx = tid & 15, ty = tid >> 4;
    const int m0 = blockIdx.y * BM;
    const int n0 = blockIdx.x * BN;

    float acc[8][8];
    #pragma unroll
    for (int i = 0; i < 8; ++i)
        #pragma unroll
        for (int j = 0; j < 8; ++j) acc[i][j] = 0.f;

    for (int k0 = 0; k0 < K; k0 += BK) {
        #pragma unroll
        for (int i = 0; i < 2; ++i) {
            int idx = tid + i * 256;
            int r = idx >> 2;            // 0..127
            int c = (idx & 3) * 4;       // 0,4,8,12
            float4 av = *(const float4*)(A + (size_t)(m0 + r) * lda + k0 + c);
            if (adapt) {
                float4 sv = *(const float4*)(adapt + k0 + c);
                av.x += sv.x; av.y += sv.y; av.z += sv.z; av.w += sv.w;
            }
            As[c + 0][r] = av.x; As[c + 1][r] = av.y;
            As[c + 2][r] = av.z; As[c + 3][r] = av.w;
            float4 bv = *(const float4*)(W + (size_t)(n0 + r) * ldw + k0 + c);
            Bs[c + 0][r] = bv.x; Bs[c + 1][r] = bv.y;
            Bs[c + 2][r] = bv.z; Bs[c + 3][r] = bv.w;
        }
        __syncthreads();
        #pragma unroll
        for (int kk = 0; kk < BK; ++kk) {
            float a[8], b[8];
            #pragma unroll
            for (int i = 0; i < 8; ++i) a[i] = As[kk][ty * 8 + i];
            #pragma unroll
            for (int j = 0; j < 8; ++j) b[j] = Bs[kk][tx * 8 + j];
            #pragma unroll
            for (int i = 0; i < 8; ++i)
                #pragma unroll
                for (int j = 0; j < 8; ++j)
                    acc[i][j] = fmaf(a[i], b[j], acc[i][j]);
        }
        __syncthreads();
    }

    #pragma unroll
    for (int i = 0; i < 8; ++i) {
        const int row = m0 + ty * 8 + i;
        #pragma unroll
        for (int j4 = 0; j4 < 2; ++j4) {
            const int col = n0 + tx * 8 + j4 * 4;
            float4 v;
            v.x = acc[i][j4 * 4 + 0]; v.y = acc[i][j4 * 4 + 1];
            v.z = acc[i][j4 * 4 + 2]; v.w = acc[i][j4 * 4 + 3];
            if (bias) {
                float4 bv = *(const float4*)(bias + col);
                v.x += bv.x; v.y += bv.y; v.z += bv.z; v.w += bv.w;
            }
            *(float4*)(C + (size_t)row * ldc + col) = v;
        }
    }
}

// ---------------------------------------------------------------------------
// Kernel 3: flash-style attention, one softmax branch per launch.
//   qkv layout: [B,S,3072] with cols [0,1024)=q, [1024,2048)=k, [2048,3072)=v
//   vbar = 0.5*(v1+v2) built on load from both qkv buffers.
//   branch 0: out  = O/l ;  branch 1: out -= O/l  (=> attn1@vbar - attn2@vbar)
//   One thread per q-row; K/V tiles of 64 keys staged in LDS (broadcast reads).
// ---------------------------------------------------------------------------
#define TKEYS 64

__global__ __launch_bounds__(256, 2) void attn_kernel(
    const float* __restrict__ qkv_b,   // branch's qkv (q,k source)
    const float* __restrict__ qkv1,    // v1 source
    const float* __restrict__ qkv2,    // v2 source
    float* __restrict__ out, int branch)
{
    __shared__ __align__(16) float ks[TKEYS][DHEAD];
    __shared__ __align__(16) float vs[TKEYS][DHEAD];
    const int tid = threadIdx.x;
    const int bh = blockIdx.y;
    const int b = bh >> 4, h = bh & 15;
    const int q = blockIdx.x * 256 + tid;

    const float* qp = qkv_b + (size_t)(b * SEQ + q) * BQKV + h * DHEAD;
    float4 qv[16];
    #pragma unroll
    for (int i = 0; i < 16; ++i) {
        float4 t = *(const float4*)(qp + i * 4);
        t.x *= ATT_SCALE; t.y *= ATT_SCALE; t.z *= ATT_SCALE; t.w *= ATT_SCALE;
        qv[i] = t;
    }
    float4 Ov[16];
    #pragma unroll
    for (int i = 0; i < 16; ++i) { Ov[i].x = 0.f; Ov[i].y = 0.f; Ov[i].z = 0.f; Ov[i].w = 0.f; }
    float m = -1e30f, l = 0.f;

    for (int kt = 0; kt < SEQ; kt += TKEYS) {
        #pragma unroll
        for (int i = 0; i < 4; ++i) {
            int idx = tid + i * 256;            // 0..1023
            int r = idx >> 4;                   // key row 0..63
            int c = (idx & 15) * 4;             // col 0..60
            size_t krow = (size_t)(b * SEQ + kt + r) * BQKV + h * DHEAD + c;
            *(float4*)&ks[r][c] = *(const float4*)(qkv_b + krow + 1024);
            float4 v1 = *(const float4*)(qkv1 + krow + 2048);
            float4 v2 = *(const float4*)(qkv2 + krow + 2048);
            float4 vb;
            vb.x = 0.5f * (v1.x + v2.x); vb.y = 0.5f * (v1.y + v2.y);
            vb.z = 0.5f * (v1.z + v2.z); vb.w = 0.5f * (v1.w + v2.w);
            *(float4*)&vs[r][c] = vb;
        }
        __syncthreads();
        for (int j = 0; j < TKEYS; ++j) {
            const float4* kr = (const float4*)ks[j];
            float s = 0.f;
            #pragma unroll
            for (int i = 0; i < 16; ++i) {
                float4 kv = kr[i];
                s = fmaf(qv[i].x, kv.x, s); s = fmaf(qv[i].y, kv.y, s);
                s = fmaf(qv[i].z, kv.z, s); s = fmaf(qv[i].w, kv.w, s);
            }
            if (s > m) {                         // rare rescale
                float sc = __expf(m - s);
                m = s;
                l *= sc;
                #pragma unroll
                for (int i = 0; i < 16; ++i) {
                    Ov[i].x *= sc; Ov[i].y *= sc; Ov[i].z *= sc; Ov[i].w *= sc;
                }
            }
            float p = __expf(s - m);
            l += p;
            const float4* vr = (const float4*)vs[j];
            #pragma unroll
            for (int i = 0; i < 16; ++i) {
                float4 vv = vr[i];
                Ov[i].x = fmaf(p, vv.x, Ov[i].x); Ov[i].y = fmaf(p, vv.y, Ov[i].y);
                Ov[i].z = fmaf(p, vv.z, Ov[i].z); Ov[i].w = fmaf(p, vv.w, Ov[i].w);
            }
        }
        __syncthreads();
    }

    const float rl = 1.f / l;
    float* op = out + (size_t)(b * SEQ + q) * DIMN + h * DHEAD;
    if (branch == 0) {
        #pragma unroll
        for (int i = 0; i < 16; ++i) {
            float4 v;
            v.x = Ov[i].x * rl; v.y = Ov[i].y * rl;
            v.z = Ov[i].z * rl; v.w = Ov[i].w * rl;
            *(float4*)(op + i * 4) = v;
        }
    } else {
        #pragma unroll
        for (int i = 0; i < 16; ++i) {
            float4 prev = *(const float4*)(op + i * 4);
            prev.x -= Ov[i].x * rl; prev.y -= Ov[i].y * rl;
            prev.z -= Ov[i].z * rl; prev.w -= Ov[i].w * rl;
            *(float4*)(op + i * 4) = prev;
        }
    }
}

// ---------------------------------------------------------------------------
// Kernel 4: LayerNorm over last dim (1024), one block per row.
// ---------------------------------------------------------------------------
__global__ __launch_bounds__(256) void ln_kernel(
    const float* __restrict__ X, const float* __restrict__ g,
    const float* __restrict__ bi, float* __restrict__ out)
{
    __shared__ float red[8];
    const int row = blockIdx.x;
    const int tid = threadIdx.x;
    const float* xp = X + (size_t)row * DIMN;
    float4 xv = *(const float4*)(xp + tid * 4);
    float s = xv.x + xv.y + xv.z + xv.w;
    #pragma unroll
    for (int off = 32; off > 0; off >>= 1) s += __shfl_down(s, off);
    const int lane = tid & 63, w = tid >> 6;
    if (lane == 0) red[w] = s;
    __syncthreads();
    const float mu = (red[0] + red[1] + red[2] + red[3]) * (1.f / DIMN);
    const float d0 = xv.x - mu, d1 = xv.y - mu, d2 = xv.z - mu, d3 = xv.w - mu;
    float sq = d0 * d0 + d1 * d1 + d2 * d2 + d3 * d3;
    #pragma unroll
    for (int off = 32; off > 0; off >>= 1) sq += __shfl_down(sq, off);
    if (lane == 0) red[4 + w] = sq;    // disjoint slots: no hazard with red[0..3] reads
    __syncthreads();
    const float var = (red[4] + red[5] + red[6] + red[7]) * (1.f / DIMN);
    const float inv = rsqrtf(var + LN_EPS);
    float4 gv = *(const float4*)(g + tid * 4);
    float4 bv = *(const float4*)(bi + tid * 4);
    float4 ov;
    ov.x = d0 * inv * gv.x + bv.x;
    ov.y = d1 * inv * gv.y + bv.y;
    ov.z = d2 * inv * gv.z + bv.z;
    ov.w = d3 * inv * gv.w + bv.w;
    *(float4*)(out + (size_t)row * DIMN + tid * 4) = ov;
}

// ---------------------------------------------------------------------------
// Launch. Workspace layout (bytes):
//   [0,4K)          svd_adapt[1024]
//   [4K, +16M)      bufA : x1p, later attn_out
//   [+16M, +16M)    bufB : x2p, later out-proj result
//   [+48M)          qkv1
//   [+48M)          qkv2
// Total ~128 MB.
// ---------------------------------------------------------------------------
extern "C" void kernel_launch(void* const* d_in, const int* in_sizes, int n_in,
                              void* d_out, int out_size, void* d_ws, size_t ws_size,
                              hipStream_t stream)
{
    const float* x     = (const float*)d_in[0];
    const float* sigma = (const float*)d_in[1];
    const float* U     = (const float*)d_in[2];
    const float* V     = (const float*)d_in[3];
    const float* Wp1   = (const float*)d_in[4];
    const float* bp1   = (const float*)d_in[5];
    const float* Wp2   = (const float*)d_in[6];
    const float* bp2   = (const float*)d_in[7];
    const float* Wqkv1 = (const float*)d_in[8];
    const float* Wqkv2 = (const float*)d_in[9];
    const float* Wout  = (const float*)d_in[10];
    const float* bout  = (const float*)d_in[11];
    const float* lng   = (const float*)d_in[12];
    const float* lnb   = (const float*)d_in[13];

    const size_t ACT = (size_t)NROWS * DIMN * sizeof(float);   // 16 MB
    const size_t QKV = (size_t)NROWS * BQKV * sizeof(float);   // 48 MB
    char* ws = (char*)d_ws;
    float* svd  = (float*)(ws);
    float* bufA = (float*)(ws + 4096);
    float* bufB = (float*)(ws + 4096 + ACT);
    float* qkv1 = (float*)(ws + 4096 + 2 * ACT);
    float* qkv2 = (float*)(ws + 4096 + 2 * ACT + QKV);

    svd_kernel<<<1, 1024, 0, stream>>>(U, V, sigma, svd);

    // x1p = (x[:, :512]+svd[:512]) @ Wp1^T + bp1   -> bufA
    gemm_nt<<<dim3(DIMN / BN, NROWS / BM), 256, 0, stream>>>(
        x, DIMN, svd, Wp1, DIMN / 2, bp1, bufA, DIMN, DIMN / 2);
    // x2p -> bufB
    gemm_nt<<<dim3(DIMN / BN, NROWS / BM), 256, 0, stream>>>(
        x + DIMN / 2, DIMN, svd + DIMN / 2, Wp2, DIMN / 2, bp2, bufB, DIMN, DIMN / 2);
    // qkv1 = x1p @ Wqkv1^T
    gemm_nt<<<dim3(BQKV / BN, NROWS / BM), 256, 0, stream>>>(
        bufA, DIMN, nullptr, Wqkv1, DIMN, nullptr, qkv1, BQKV, DIMN);
    // qkv2 = x2p @ Wqkv2^T
    gemm_nt<<<dim3(BQKV / BN, NROWS / BM), 256, 0, stream>>>(
        bufB, DIMN, nullptr, Wqkv2, DIMN, nullptr, qkv2, BQKV, DIMN);

    // attention: bufA = attn1@vbar, then bufA -= attn2@vbar
    attn_kernel<<<dim3(SEQ / 256, BATCH * HEADS), 256, 0, stream>>>(qkv1, qkv1, qkv2, bufA, 0);
    attn_kernel<<<dim3(SEQ / 256, BATCH * HEADS), 256, 0, stream>>>(qkv2, qkv1, qkv2, bufA, 1);

    // out-proj: bufB = bufA @ Wout^T + bout
    gemm_nt<<<dim3(DIMN / BN, NROWS / BM), 256, 0, stream>>>(
        bufA, DIMN, nullptr, Wout, DIMN, bout, bufB, DIMN, DIMN);

    // LayerNorm -> d_out
    ln_kernel<<<NROWS, 256, 0, stream>>>(bufB, lng, lnb, (float*)d_out);
}

// Round 2
// 1671.408 us; speedup vs baseline: 1.2874x; 1.2874x over previous
//
#include <hip/hip_runtime.h>
#include <hip/hip_bf16.h>
#include <math.h>

// Problem constants (fixed by the reference)
#define DIMN   1024
#define HEADS  16
#define DHEAD  64
#define BQKV   3072
#define BATCH  4
#define SEQ    1024
#define NROWS  (BATCH * SEQ)     // 4096
#define ATT_SCALE 0.125f         // 1/sqrt(64)
#define LN_EPS 1e-5f

// ---------------------------------------------------------------------------
// Kernel 1: svd_adapt[d] = sigma * sum_r U[d,r] * (sum_j V[r,j])
// ---------------------------------------------------------------------------
__global__ __launch_bounds__(1024) void svd_kernel(
    const float* __restrict__ U, const float* __restrict__ V,
    const float* __restrict__ sigma_p, float* __restrict__ svd)
{
    __shared__ float part[16][4];
    __shared__ float vsum[4];
    const int tid = threadIdx.x;          // 0..1023
    float v0 = V[0 * DIMN + tid];
    float v1 = V[1 * DIMN + tid];
    float v2 = V[2 * DIMN + tid];
    float v3 = V[3 * DIMN + tid];
    #pragma unroll
    for (int off = 32; off > 0; off >>= 1) {
        v0 += __shfl_down(v0, off);
        v1 += __shfl_down(v1, off);
        v2 += __shfl_down(v2, off);
        v3 += __shfl_down(v3, off);
    }
    const int lane = tid & 63, w = tid >> 6;
    if (lane == 0) { part[w][0] = v0; part[w][1] = v1; part[w][2] = v2; part[w][3] = v3; }
    __syncthreads();
    if (tid < 4) {
        float s = 0.f;
        #pragma unroll
        for (int i = 0; i < 16; ++i) s += part[i][tid];
        vsum[tid] = s;
    }
    __syncthreads();
    const float sg = sigma_p[0];
    float acc = U[tid * 4 + 0] * vsum[0] + U[tid * 4 + 1] * vsum[1]
              + U[tid * 4 + 2] * vsum[2] + U[tid * 4 + 3] * vsum[3];
    svd[tid] = sg * acc;
}

// ---------------------------------------------------------------------------
// Kernel 2: generic C = (A (+adapt)) @ W^T (+bias)  — unchanged this round.
// ---------------------------------------------------------------------------
#define BM 128
#define BN 128
#define BK 16

__global__ __launch_bounds__(256) void gemm_nt(
    const float* __restrict__ A, int lda,
    const float* __restrict__ adapt,          // nullable, length K, added to A cols
    const float* __restrict__ W, int ldw,
    const float* __restrict__ bias,           // nullable, length N
    float* __restrict__ C, int ldc, int K)
{
    __shared__ __align__(16) float As[BK][BM + 4];
    __shared__ __align__(16) float Bs[BK][BN + 4];
    const int tid = threadIdx.x;
    const int tx = tid & 15, ty = tid >> 4;
    const int m0 = blockIdx.y * BM;
    const int n0 = blockIdx.x * BN;

    float acc[8][8];
    #pragma unroll
    for (int i = 0; i < 8; ++i)
        #pragma unroll
        for (int j = 0; j < 8; ++j) acc[i][j] = 0.f;

    for (int k0 = 0; k0 < K; k0 += BK) {
        #pragma unroll
        for (int i = 0; i < 2; ++i) {
            int idx = tid + i * 256;
            int r = idx >> 2;            // 0..127
            int c = (idx & 3) * 4;       // 0,4,8,12
            float4 av = *(const float4*)(A + (size_t)(m0 + r) * lda + k0 + c);
            if (adapt) {
                float4 sv = *(const float4*)(adapt + k0 + c);
                av.x += sv.x; av.y += sv.y; av.z += sv.z; av.w += sv.w;
            }
            As[c + 0][r] = av.x; As[c + 1][r] = av.y;
            As[c + 2][r] = av.z; As[c + 3][r] = av.w;
            float4 bv = *(const float4*)(W + (size_t)(n0 + r) * ldw + k0 + c);
            Bs[c + 0][r] = bv.x; Bs[c + 1][r] = bv.y;
            Bs[c + 2][r] = bv.z; Bs[c + 3][r] = bv.w;
        }
        __syncthreads();
        #pragma unroll
        for (int kk = 0; kk < BK; ++kk) {
            float a[8], b[8];
            #pragma unroll
            for (int i = 0; i < 8; ++i) a[i] = As[kk][ty * 8 + i];
            #pragma unroll
            for (int j = 0; j < 8; ++j) b[j] = Bs[kk][tx * 8 + j];
            #pragma unroll
            for (int i = 0; i < 8; ++i)
                #pragma unroll
                for (int j = 0; j < 8; ++j)
                    acc[i][j] = fmaf(a[i], b[j], acc[i][j]);
        }
        __syncthreads();
    }

    #pragma unroll
    for (int i = 0; i < 8; ++i) {
        const int row = m0 + ty * 8 + i;
        #pragma unroll
        for (int j4 = 0; j4 < 2; ++j4) {
            const int col = n0 + tx * 8 + j4 * 4;
            float4 v;
            v.x = acc[i][j4 * 4 + 0]; v.y = acc[i][j4 * 4 + 1];
            v.z = acc[i][j4 * 4 + 2]; v.w = acc[i][j4 * 4 + 3];
            if (bias) {
                float4 bv = *(const float4*)(bias + col);
                v.x += bv.x; v.y += bv.y; v.z += bv.z; v.w += bv.w;
            }
            *(float4*)(C + (size_t)row * ldc + col) = v;
        }
    }
}

// ---------------------------------------------------------------------------
// Kernel 3: FUSED differential flash attention, both branches in one pass.
//   4 threads per q-row, each owning 16 of the 64 head dims. Score reduced
//   across the 4 lanes via __shfl_xor. Grid (SEQ/64, B*H) = 1024 blocks
//   -> 4096 waves = 16 waves/CU (vs 4 before).
//   out = O1/l1 - O2/l2, written once (no read-modify-write).
// ---------------------------------------------------------------------------
#define TK 32   // keys per LDS tile; LDS = 3*32*64*4 = 24 KB

__global__ __launch_bounds__(256, 4) void attn_fused(
    const float* __restrict__ qkv1,
    const float* __restrict__ qkv2,
    float* __restrict__ out)
{
    __shared__ __align__(16) float k1s[TK][DHEAD];
    __shared__ __align__(16) float k2s[TK][DHEAD];
    __shared__ __align__(16) float vs[TK][DHEAD];
    const int tid = threadIdx.x;
    const int r  = tid >> 2;              // q-row within block, 0..63
    const int c4 = tid & 3;               // dim chunk: dims [c4*16, c4*16+16)
    const int bh = blockIdx.y;
    const int b = bh >> 4, h = bh & 15;
    const int q = blockIdx.x * 64 + r;

    const size_t qoff = (size_t)(b * SEQ + q) * BQKV + h * DHEAD + c4 * 16;
    float4 q1[4], q2[4];
    #pragma unroll
    for (int i = 0; i < 4; ++i) {
        float4 t = *(const float4*)(qkv1 + qoff + i * 4);
        t.x *= ATT_SCALE; t.y *= ATT_SCALE; t.z *= ATT_SCALE; t.w *= ATT_SCALE;
        q1[i] = t;
        t = *(const float4*)(qkv2 + qoff + i * 4);
        t.x *= ATT_SCALE; t.y *= ATT_SCALE; t.z *= ATT_SCALE; t.w *= ATT_SCALE;
        q2[i] = t;
    }
    float4 O1[4], O2[4];
    #pragma unroll
    for (int i = 0; i < 4; ++i) {
        O1[i].x = O1[i].y = O1[i].z = O1[i].w = 0.f;
        O2[i].x = O2[i].y = O2[i].z = O2[i].w = 0.f;
    }
    float m1 = -1e30f, l1 = 0.f, m2 = -1e30f, l2 = 0.f;

    for (int kt = 0; kt < SEQ; kt += TK) {
        // stage k1, k2, vbar tiles: 512 float4 per array over 256 threads
        #pragma unroll
        for (int i = 0; i < 2; ++i) {
            int idx = tid + i * 256;          // 0..511
            int kr = idx >> 4;                // 0..31
            int kc = (idx & 15) * 4;          // 0..60
            size_t base = (size_t)(b * SEQ + kt + kr) * BQKV + h * DHEAD + kc;
            *(float4*)&k1s[kr][kc] = *(const float4*)(qkv1 + base + 1024);
            *(float4*)&k2s[kr][kc] = *(const float4*)(qkv2 + base + 1024);
            float4 v1 = *(const float4*)(qkv1 + base + 2048);
            float4 v2 = *(const float4*)(qkv2 + base + 2048);
            float4 vb;
            vb.x = 0.5f * (v1.x + v2.x); vb.y = 0.5f * (v1.y + v2.y);
            vb.z = 0.5f * (v1.z + v2.z); vb.w = 0.5f * (v1.w + v2.w);
            *(float4*)&vs[kr][kc] = vb;
        }
        __syncthreads();

        for (int j = 0; j < TK; ++j) {
            const float4* kr1 = (const float4*)(&k1s[j][c4 * 16]);
            const float4* kr2 = (const float4*)(&k2s[j][c4 * 16]);
            float s1 = 0.f, s2 = 0.f;
            #pragma unroll
            for (int i = 0; i < 4; ++i) {
                float4 kv = kr1[i];
                s1 = fmaf(q1[i].x, kv.x, s1); s1 = fmaf(q1[i].y, kv.y, s1);
                s1 = fmaf(q1[i].z, kv.z, s1); s1 = fmaf(q1[i].w, kv.w, s1);
                float4 kw = kr2[i];
                s2 = fmaf(q2[i].x, kw.x, s2); s2 = fmaf(q2[i].y, kw.y, s2);
                s2 = fmaf(q2[i].z, kw.z, s2); s2 = fmaf(q2[i].w, kw.w, s2);
            }
            // reduce partial dots across the 4 lanes of this q-row
            s1 += __shfl_xor(s1, 1); s1 += __shfl_xor(s1, 2);
            s2 += __shfl_xor(s2, 1); s2 += __shfl_xor(s2, 2);

            if (s1 > m1) {
                float sc = __expf(m1 - s1); m1 = s1; l1 *= sc;
                #pragma unroll
                for (int i = 0; i < 4; ++i) {
                    O1[i].x *= sc; O1[i].y *= sc; O1[i].z *= sc; O1[i].w *= sc;
                }
            }
            float p1 = __expf(s1 - m1); l1 += p1;
            if (s2 > m2) {
                float sc = __expf(m2 - s2); m2 = s2; l2 *= sc;
                #pragma unroll
                for (int i = 0; i < 4; ++i) {
                    O2[i].x *= sc; O2[i].y *= sc; O2[i].z *= sc; O2[i].w *= sc;
                }
            }
            float p2 = __expf(s2 - m2); l2 += p2;

            const float4* vr = (const float4*)(&vs[j][c4 * 16]);
            #pragma unroll
            for (int i = 0; i < 4; ++i) {
                float4 vv = vr[i];
                O1[i].x = fmaf(p1, vv.x, O1[i].x); O1[i].y = fmaf(p1, vv.y, O1[i].y);
                O1[i].z = fmaf(p1, vv.z, O1[i].z); O1[i].w = fmaf(p1, vv.w, O1[i].w);
                O2[i].x = fmaf(p2, vv.x, O2[i].x); O2[i].y = fmaf(p2, vv.y, O2[i].y);
                O2[i].z = fmaf(p2, vv.z, O2[i].z); O2[i].w = fmaf(p2, vv.w, O2[i].w);
            }
        }
        __syncthreads();
    }

    const float rl1 = 1.f / l1, rl2 = 1.f / l2;
    float* op = out + (size_t)(b * SEQ + q) * DIMN + h * DHEAD + c4 * 16;
    #pragma unroll
    for (int i = 0; i < 4; ++i) {
        float4 v;
        v.x = O1[i].x * rl1 - O2[i].x * rl2;
        v.y = O1[i].y * rl1 - O2[i].y * rl2;
        v.z = O1[i].z * rl1 - O2[i].z * rl2;
        v.w = O1[i].w * rl1 - O2[i].w * rl2;
        *(float4*)(op + i * 4) = v;
    }
}

// ---------------------------------------------------------------------------
// Kernel 4: LayerNorm over last dim (1024), one block per row.
//   (race fixed: barrier before reading the variance partials)
// ---------------------------------------------------------------------------
__global__ __launch_bounds__(256) void ln_kernel(
    const float* __restrict__ X, const float* __restrict__ g,
    const float* __restrict__ bi, float* __restrict__ out)
{
    __shared__ float red[8];
    const int row = blockIdx.x;
    const int tid = threadIdx.x;
    const float* xp = X + (size_t)row * DIMN;
    float4 xv = *(const float4*)(xp + tid * 4);
    float s = xv.x + xv.y + xv.z + xv.w;
    #pragma unroll
    for (int off = 32; off > 0; off >>= 1) s += __shfl_down(s, off);
    const int lane = tid & 63, w = tid >> 6;
    if (lane == 0) red[w] = s;
    __syncthreads();
    const float mu = (red[0] + red[1] + red[2] + red[3]) * (1.f / DIMN);
    const float d0 = xv.x - mu, d1 = xv.y - mu, d2 = xv.z - mu, d3 = xv.w - mu;
    float sq = d0 * d0 + d1 * d1 + d2 * d2 + d3 * d3;
    #pragma unroll
    for (int off = 32; off > 0; off >>= 1) sq += __shfl_down(sq, off);
    if (lane == 0) red[4 + w] = sq;
    __syncthreads();   // visibility of red[4..7] across waves
    const float var = (red[4] + red[5] + red[6] + red[7]) * (1.f / DIMN);
    const float inv = rsqrtf(var + LN_EPS);
    float4 gv = *(const float4*)(g + tid * 4);
    float4 bv = *(const float4*)(bi + tid * 4);
    float4 ov;
    ov.x = d0 * inv * gv.x + bv.x;
    ov.y = d1 * inv * gv.y + bv.y;
    ov.z = d2 * inv * gv.z + bv.z;
    ov.w = d3 * inv * gv.w + bv.w;
    *(float4*)(out + (size_t)row * DIMN + tid * 4) = ov;
}

// ---------------------------------------------------------------------------
// Launch. Workspace layout (bytes):
//   [0,4K)          svd_adapt[1024]
//   [4K, +16M)      bufA : x1p, later attn_out
//   [+16M, +16M)    bufB : x2p, later out-proj result
//   [+48M)          qkv1
//   [+48M)          qkv2
// ---------------------------------------------------------------------------
extern "C" void kernel_launch(void* const* d_in, const int* in_sizes, int n_in,
                              void* d_out, int out_size, void* d_ws, size_t ws_size,
                              hipStream_t stream)
{
    const float* x     = (const float*)d_in[0];
    const float* sigma = (const float*)d_in[1];
    const float* U     = (const float*)d_in[2];
    const float* V     = (const float*)d_in[3];
    const float* Wp1   = (const float*)d_in[4];
    const float* bp1   = (const float*)d_in[5];
    const float* Wp2   = (const float*)d_in[6];
    const float* bp2   = (const float*)d_in[7];
    const float* Wqkv1 = (const float*)d_in[8];
    const float* Wqkv2 = (const float*)d_in[9];
    const float* Wout  = (const float*)d_in[10];
    const float* bout  = (const float*)d_in[11];
    const float* lng   = (const float*)d_in[12];
    const float* lnb   = (const float*)d_in[13];

    const size_t ACT = (size_t)NROWS * DIMN * sizeof(float);   // 16 MB
    const size_t QKV = (size_t)NROWS * BQKV * sizeof(float);   // 48 MB
    char* ws = (char*)d_ws;
    float* svd  = (float*)(ws);
    float* bufA = (float*)(ws + 4096);
    float* bufB = (float*)(ws + 4096 + ACT);
    float* qkv1 = (float*)(ws + 4096 + 2 * ACT);
    float* qkv2 = (float*)(ws + 4096 + 2 * ACT + QKV);

    svd_kernel<<<1, 1024, 0, stream>>>(U, V, sigma, svd);

    // x1p = (x[:, :512]+svd[:512]) @ Wp1^T + bp1   -> bufA
    gemm_nt<<<dim3(DIMN / BN, NROWS / BM), 256, 0, stream>>>(
        x, DIMN, svd, Wp1, DIMN / 2, bp1, bufA, DIMN, DIMN / 2);
    // x2p -> bufB
    gemm_nt<<<dim3(DIMN / BN, NROWS / BM), 256, 0, stream>>>(
        x + DIMN / 2, DIMN, svd + DIMN / 2, Wp2, DIMN / 2, bp2, bufB, DIMN, DIMN / 2);
    // qkv1 = x1p @ Wqkv1^T
    gemm_nt<<<dim3(BQKV / BN, NROWS / BM), 256, 0, stream>>>(
        bufA, DIMN, nullptr, Wqkv1, DIMN, nullptr, qkv1, BQKV, DIMN);
    // qkv2 = x2p @ Wqkv2^T
    gemm_nt<<<dim3(BQKV / BN, NROWS / BM), 256, 0, stream>>>(
        bufB, DIMN, nullptr, Wqkv2, DIMN, nullptr, qkv2, BQKV, DIMN);

    // fused differential attention -> bufA
    attn_fused<<<dim3(SEQ / 64, BATCH * HEADS), 256, 0, stream>>>(qkv1, qkv2, bufA);

    // out-proj: bufB = bufA @ Wout^T + bout
    gemm_nt<<<dim3(DIMN / BN, NROWS / BM), 256, 0, stream>>>(
        bufA, DIMN, nullptr, Wout, DIMN, bout, bufB, DIMN, DIMN);

    // LayerNorm -> d_out
    ln_kernel<<<NROWS, 256, 0, stream>>>(bufB, lng, lnb, (float*)d_out);
}

// Round 3
// 1159.980 us; speedup vs baseline: 1.8550x; 1.4409x over previous
//
#include <hip/hip_runtime.h>
#include <hip/hip_bf16.h>
#include <math.h>

// Problem constants (fixed by the reference)
#define DIMN   1024
#define HEADS  16
#define DHEAD  64
#define BQKV   3072
#define BATCH  4
#define SEQ    1024
#define NROWS  (BATCH * SEQ)     // 4096
#define ATT_SCALE 0.125f         // 1/sqrt(64)
#define LN_EPS 1e-5f

typedef __attribute__((ext_vector_type(8))) short  bf16x8;
typedef __attribute__((ext_vector_type(4))) float  f32x4;
typedef __attribute__((ext_vector_type(4))) unsigned short u16x4;

// fp32 -> bf16 round-to-nearest-even
__device__ __forceinline__ unsigned short f2bf(float f) {
    unsigned u = __float_as_uint(f);
    u += 0x7FFFu + ((u >> 16) & 1u);
    return (unsigned short)(u >> 16);
}

// ---------------------------------------------------------------------------
// Kernel 1: svd_adapt[d] = sigma * sum_r U[d,r] * (sum_j V[r,j])
// ---------------------------------------------------------------------------
__global__ __launch_bounds__(1024) void svd_kernel(
    const float* __restrict__ U, const float* __restrict__ V,
    const float* __restrict__ sigma_p, float* __restrict__ svd)
{
    __shared__ float part[16][4];
    __shared__ float vsum[4];
    const int tid = threadIdx.x;          // 0..1023
    float v0 = V[0 * DIMN + tid];
    float v1 = V[1 * DIMN + tid];
    float v2 = V[2 * DIMN + tid];
    float v3 = V[3 * DIMN + tid];
    #pragma unroll
    for (int off = 32; off > 0; off >>= 1) {
        v0 += __shfl_down(v0, off);
        v1 += __shfl_down(v1, off);
        v2 += __shfl_down(v2, off);
        v3 += __shfl_down(v3, off);
    }
    const int lane = tid & 63, w = tid >> 6;
    if (lane == 0) { part[w][0] = v0; part[w][1] = v1; part[w][2] = v2; part[w][3] = v3; }
    __syncthreads();
    if (tid < 4) {
        float s = 0.f;
        #pragma unroll
        for (int i = 0; i < 16; ++i) s += part[i][tid];
        vsum[tid] = s;
    }
    __syncthreads();
    const float sg = sigma_p[0];
    float acc = U[tid * 4 + 0] * vsum[0] + U[tid * 4 + 1] * vsum[1]
              + U[tid * 4 + 2] * vsum[2] + U[tid * 4 + 3] * vsum[3];
    svd[tid] = sg * acc;
}

// ---------------------------------------------------------------------------
// Kernel 2: bf16-MFMA GEMM  C = (A (+adapt)) @ W^T (+bias), fp32 accum.
//   A: [M,K] fp32 row-major (lda), W: [N,K] fp32 row-major (ldw), C: [M,N].
//   Tile 128x128xBK64, 4 waves in 2x2, each wave 64x64 = 4x4 frags of
//   16x16x32. fp32->bf16 RNE conversion happens in the staging path.
//   LDS layout: [row][64] bf16 rows of 128B, 16B-unit XOR swizzle by (row&7)
//   -> conflict-free ds_read_b128 fragments (2-way only, free).
// ---------------------------------------------------------------------------
#define GBM 128
#define GBN 128
#define GBK 64

__global__ __launch_bounds__(256, 2) void gemm_mfma(
    const float* __restrict__ A, int lda,
    const float* __restrict__ adapt,          // nullable, length K
    const float* __restrict__ W, int ldw,
    const float* __restrict__ bias,           // nullable, length N
    float* __restrict__ C, int ldc, int K)
{
    __shared__ __align__(16) short As[GBM * GBK];   // 16 KB
    __shared__ __align__(16) short Bs[GBN * GBK];   // 16 KB
    const int tid = threadIdx.x;
    const int m0 = blockIdx.y * GBM;
    const int n0 = blockIdx.x * GBN;
    const int lane = tid & 63;
    const int wv = tid >> 6;
    const int wr = wv >> 1, wc = wv & 1;      // wave quadrant
    const int lr = lane & 15;                 // row-in-fragment
    const int kg = lane >> 4;                 // k-group 0..3

    f32x4 acc[4][4];
    #pragma unroll
    for (int i = 0; i < 4; ++i)
        #pragma unroll
        for (int j = 0; j < 4; ++j)
            acc[i][j] = (f32x4){0.f, 0.f, 0.f, 0.f};

    for (int k0 = 0; k0 < K; k0 += GBK) {
        // ---- stage A tile (128 rows x 64 cols) fp32 -> bf16, swizzled ----
        #pragma unroll
        for (int i = 0; i < 8; ++i) {
            int flat = i * 256 + tid;             // 0..2047
            int r  = flat >> 4;                   // row 0..127
            int c4 = flat & 15;                   // float4 index 0..15
            float4 av = *(const float4*)(A + (size_t)(m0 + r) * lda + k0 + c4 * 4);
            if (adapt) {
                float4 sv = *(const float4*)(adapt + k0 + c4 * 4);
                av.x += sv.x; av.y += sv.y; av.z += sv.z; av.w += sv.w;
            }
            u16x4 h;
            h[0] = f2bf(av.x); h[1] = f2bf(av.y); h[2] = f2bf(av.z); h[3] = f2bf(av.w);
            int boff = r * 128 + ((((c4 >> 1) ^ (r & 7)) << 4) | ((c4 & 1) << 3));
            *(u16x4*)((char*)As + boff) = h;
        }
        // ---- stage W tile (128 rows x 64 cols) ----
        #pragma unroll
        for (int i = 0; i < 8; ++i) {
            int flat = i * 256 + tid;
            int r  = flat >> 4;
            int c4 = flat & 15;
            float4 wv4 = *(const float4*)(W + (size_t)(n0 + r) * ldw + k0 + c4 * 4);
            u16x4 h;
            h[0] = f2bf(wv4.x); h[1] = f2bf(wv4.y); h[2] = f2bf(wv4.z); h[3] = f2bf(wv4.w);
            int boff = r * 128 + ((((c4 >> 1) ^ (r & 7)) << 4) | ((c4 & 1) << 3));
            *(u16x4*)((char*)Bs + boff) = h;
        }
        __syncthreads();

        // ---- MFMA: 2 k-steps of 32, 4x4 fragments per wave ----
        #pragma unroll
        for (int ks = 0; ks < 2; ++ks) {
            bf16x8 a[4], b[4];
            #pragma unroll
            for (int mi = 0; mi < 4; ++mi) {
                int row = wr * 64 + mi * 16 + lr;
                int boff = row * 128 + (((ks * 4 + kg) ^ (row & 7)) << 4);
                a[mi] = *(const bf16x8*)((const char*)As + boff);
            }
            #pragma unroll
            for (int ni = 0; ni < 4; ++ni) {
                int row = wc * 64 + ni * 16 + lr;
                int boff = row * 128 + (((ks * 4 + kg) ^ (row & 7)) << 4);
                b[ni] = *(const bf16x8*)((const char*)Bs + boff);
            }
            #pragma unroll
            for (int mi = 0; mi < 4; ++mi)
                #pragma unroll
                for (int ni = 0; ni < 4; ++ni)
                    acc[mi][ni] = __builtin_amdgcn_mfma_f32_16x16x32_bf16(
                        a[mi], b[ni], acc[mi][ni], 0, 0, 0);
        }
        __syncthreads();
    }

    // ---- C write: D row = kg*4 + reg, col = lr (m89-verified layout) ----
    #pragma unroll
    for (int ni = 0; ni < 4; ++ni) {
        const int col = n0 + wc * 64 + ni * 16 + lr;
        const float bs = bias ? bias[col] : 0.f;
        #pragma unroll
        for (int mi = 0; mi < 4; ++mi) {
            const int row = m0 + wr * 64 + mi * 16 + kg * 4;
            #pragma unroll
            for (int r = 0; r < 4; ++r)
                C[(size_t)(row + r) * ldc + col] = acc[mi][ni][r] + bs;
        }
    }
}

// ---------------------------------------------------------------------------
// Kernel 3: FUSED differential flash attention (unchanged this round).
// ---------------------------------------------------------------------------
#define TK 32   // keys per LDS tile; LDS = 3*32*64*4 = 24 KB

__global__ __launch_bounds__(256, 4) void attn_fused(
    const float* __restrict__ qkv1,
    const float* __restrict__ qkv2,
    float* __restrict__ out)
{
    __shared__ __align__(16) float k1s[TK][DHEAD];
    __shared__ __align__(16) float k2s[TK][DHEAD];
    __shared__ __align__(16) float vs[TK][DHEAD];
    const int tid = threadIdx.x;
    const int r  = tid >> 2;              // q-row within block, 0..63
    const int c4 = tid & 3;               // dim chunk: dims [c4*16, c4*16+16)
    const int bh = blockIdx.y;
    const int b = bh >> 4, h = bh & 15;
    const int q = blockIdx.x * 64 + r;

    const size_t qoff = (size_t)(b * SEQ + q) * BQKV + h * DHEAD + c4 * 16;
    float4 q1[4], q2[4];
    #pragma unroll
    for (int i = 0; i < 4; ++i) {
        float4 t = *(const float4*)(qkv1 + qoff + i * 4);
        t.x *= ATT_SCALE; t.y *= ATT_SCALE; t.z *= ATT_SCALE; t.w *= ATT_SCALE;
        q1[i] = t;
        t = *(const float4*)(qkv2 + qoff + i * 4);
        t.x *= ATT_SCALE; t.y *= ATT_SCALE; t.z *= ATT_SCALE; t.w *= ATT_SCALE;
        q2[i] = t;
    }
    float4 O1[4], O2[4];
    #pragma unroll
    for (int i = 0; i < 4; ++i) {
        O1[i].x = O1[i].y = O1[i].z = O1[i].w = 0.f;
        O2[i].x = O2[i].y = O2[i].z = O2[i].w = 0.f;
    }
    float m1 = -1e30f, l1 = 0.f, m2 = -1e30f, l2 = 0.f;

    for (int kt = 0; kt < SEQ; kt += TK) {
        #pragma unroll
        for (int i = 0; i < 2; ++i) {
            int idx = tid + i * 256;          // 0..511
            int kr = idx >> 4;                // 0..31
            int kc = (idx & 15) * 4;          // 0..60
            size_t base = (size_t)(b * SEQ + kt + kr) * BQKV + h * DHEAD + kc;
            *(float4*)&k1s[kr][kc] = *(const float4*)(qkv1 + base + 1024);
            *(float4*)&k2s[kr][kc] = *(const float4*)(qkv2 + base + 1024);
            float4 v1 = *(const float4*)(qkv1 + base + 2048);
            float4 v2 = *(const float4*)(qkv2 + base + 2048);
            float4 vb;
            vb.x = 0.5f * (v1.x + v2.x); vb.y = 0.5f * (v1.y + v2.y);
            vb.z = 0.5f * (v1.z + v2.z); vb.w = 0.5f * (v1.w + v2.w);
            *(float4*)&vs[kr][kc] = vb;
        }
        __syncthreads();

        for (int j = 0; j < TK; ++j) {
            const float4* kr1 = (const float4*)(&k1s[j][c4 * 16]);
            const float4* kr2 = (const float4*)(&k2s[j][c4 * 16]);
            float s1 = 0.f, s2 = 0.f;
            #pragma unroll
            for (int i = 0; i < 4; ++i) {
                float4 kv = kr1[i];
                s1 = fmaf(q1[i].x, kv.x, s1); s1 = fmaf(q1[i].y, kv.y, s1);
                s1 = fmaf(q1[i].z, kv.z, s1); s1 = fmaf(q1[i].w, kv.w, s1);
                float4 kw = kr2[i];
                s2 = fmaf(q2[i].x, kw.x, s2); s2 = fmaf(q2[i].y, kw.y, s2);
                s2 = fmaf(q2[i].z, kw.z, s2); s2 = fmaf(q2[i].w, kw.w, s2);
            }
            s1 += __shfl_xor(s1, 1); s1 += __shfl_xor(s1, 2);
            s2 += __shfl_xor(s2, 1); s2 += __shfl_xor(s2, 2);

            if (s1 > m1) {
                float sc = __expf(m1 - s1); m1 = s1; l1 *= sc;
                #pragma unroll
                for (int i = 0; i < 4; ++i) {
                    O1[i].x *= sc; O1[i].y *= sc; O1[i].z *= sc; O1[i].w *= sc;
                }
            }
            float p1 = __expf(s1 - m1); l1 += p1;
            if (s2 > m2) {
                float sc = __expf(m2 - s2); m2 = s2; l2 *= sc;
                #pragma unroll
                for (int i = 0; i < 4; ++i) {
                    O2[i].x *= sc; O2[i].y *= sc; O2[i].z *= sc; O2[i].w *= sc;
                }
            }
            float p2 = __expf(s2 - m2); l2 += p2;

            const float4* vr = (const float4*)(&vs[j][c4 * 16]);
            #pragma unroll
            for (int i = 0; i < 4; ++i) {
                float4 vv = vr[i];
                O1[i].x = fmaf(p1, vv.x, O1[i].x); O1[i].y = fmaf(p1, vv.y, O1[i].y);
                O1[i].z = fmaf(p1, vv.z, O1[i].z); O1[i].w = fmaf(p1, vv.w, O1[i].w);
                O2[i].x = fmaf(p2, vv.x, O2[i].x); O2[i].y = fmaf(p2, vv.y, O2[i].y);
                O2[i].z = fmaf(p2, vv.z, O2[i].z); O2[i].w = fmaf(p2, vv.w, O2[i].w);
            }
        }
        __syncthreads();
    }

    const float rl1 = 1.f / l1, rl2 = 1.f / l2;
    float* op = out + (size_t)(b * SEQ + q) * DIMN + h * DHEAD + c4 * 16;
    #pragma unroll
    for (int i = 0; i < 4; ++i) {
        float4 v;
        v.x = O1[i].x * rl1 - O2[i].x * rl2;
        v.y = O1[i].y * rl1 - O2[i].y * rl2;
        v.z = O1[i].z * rl1 - O2[i].z * rl2;
        v.w = O1[i].w * rl1 - O2[i].w * rl2;
        *(float4*)(op + i * 4) = v;
    }
}

// ---------------------------------------------------------------------------
// Kernel 4: LayerNorm over last dim (1024), one block per row.
// ---------------------------------------------------------------------------
__global__ __launch_bounds__(256) void ln_kernel(
    const float* __restrict__ X, const float* __restrict__ g,
    const float* __restrict__ bi, float* __restrict__ out)
{
    __shared__ float red[8];
    const int row = blockIdx.x;
    const int tid = threadIdx.x;
    const float* xp = X + (size_t)row * DIMN;
    float4 xv = *(const float4*)(xp + tid * 4);
    float s = xv.x + xv.y + xv.z + xv.w;
    #pragma unroll
    for (int off = 32; off > 0; off >>= 1) s += __shfl_down(s, off);
    const int lane = tid & 63, w = tid >> 6;
    if (lane == 0) red[w] = s;
    __syncthreads();
    const float mu = (red[0] + red[1] + red[2] + red[3]) * (1.f / DIMN);
    const float d0 = xv.x - mu, d1 = xv.y - mu, d2 = xv.z - mu, d3 = xv.w - mu;
    float sq = d0 * d0 + d1 * d1 + d2 * d2 + d3 * d3;
    #pragma unroll
    for (int off = 32; off > 0; off >>= 1) sq += __shfl_down(sq, off);
    if (lane == 0) red[4 + w] = sq;
    __syncthreads();
    const float var = (red[4] + red[5] + red[6] + red[7]) * (1.f / DIMN);
    const float inv = rsqrtf(var + LN_EPS);
    float4 gv = *(const float4*)(g + tid * 4);
    float4 bv = *(const float4*)(bi + tid * 4);
    float4 ov;
    ov.x = d0 * inv * gv.x + bv.x;
    ov.y = d1 * inv * gv.y + bv.y;
    ov.z = d2 * inv * gv.z + bv.z;
    ov.w = d3 * inv * gv.w + bv.w;
    *(float4*)(out + (size_t)row * DIMN + tid * 4) = ov;
}

// ---------------------------------------------------------------------------
// Launch. Workspace layout (bytes):
//   [0,4K)          svd_adapt[1024]
//   [4K, +16M)      bufA : x1p, later attn_out
//   [+16M, +16M)    bufB : x2p, later out-proj result
//   [+48M)          qkv1
//   [+48M)          qkv2
// ---------------------------------------------------------------------------
extern "C" void kernel_launch(void* const* d_in, const int* in_sizes, int n_in,
                              void* d_out, int out_size, void* d_ws, size_t ws_size,
                              hipStream_t stream)
{
    const float* x     = (const float*)d_in[0];
    const float* sigma = (const float*)d_in[1];
    const float* U     = (const float*)d_in[2];
    const float* V     = (const float*)d_in[3];
    const float* Wp1   = (const float*)d_in[4];
    const float* bp1   = (const float*)d_in[5];
    const float* Wp2   = (const float*)d_in[6];
    const float* bp2   = (const float*)d_in[7];
    const float* Wqkv1 = (const float*)d_in[8];
    const float* Wqkv2 = (const float*)d_in[9];
    const float* Wout  = (const float*)d_in[10];
    const float* bout  = (const float*)d_in[11];
    const float* lng   = (const float*)d_in[12];
    const float* lnb   = (const float*)d_in[13];

    const size_t ACT = (size_t)NROWS * DIMN * sizeof(float);   // 16 MB
    const size_t QKV = (size_t)NROWS * BQKV * sizeof(float);   // 48 MB
    char* ws = (char*)d_ws;
    float* svd  = (float*)(ws);
    float* bufA = (float*)(ws + 4096);
    float* bufB = (float*)(ws + 4096 + ACT);
    float* qkv1 = (float*)(ws + 4096 + 2 * ACT);
    float* qkv2 = (float*)(ws + 4096 + 2 * ACT + QKV);

    svd_kernel<<<1, 1024, 0, stream>>>(U, V, sigma, svd);

    // x1p = (x[:, :512]+svd[:512]) @ Wp1^T + bp1   -> bufA
    gemm_mfma<<<dim3(DIMN / GBN, NROWS / GBM), 256, 0, stream>>>(
        x, DIMN, svd, Wp1, DIMN / 2, bp1, bufA, DIMN, DIMN / 2);
    // x2p -> bufB
    gemm_mfma<<<dim3(DIMN / GBN, NROWS / GBM), 256, 0, stream>>>(
        x + DIMN / 2, DIMN, svd + DIMN / 2, Wp2, DIMN / 2, bp2, bufB, DIMN, DIMN / 2);
    // qkv1 = x1p @ Wqkv1^T
    gemm_mfma<<<dim3(BQKV / GBN, NROWS / GBM), 256, 0, stream>>>(
        bufA, DIMN, nullptr, Wqkv1, DIMN, nullptr, qkv1, BQKV, DIMN);
    // qkv2 = x2p @ Wqkv2^T
    gemm_mfma<<<dim3(BQKV / GBN, NROWS / GBM), 256, 0, stream>>>(
        bufB, DIMN, nullptr, Wqkv2, DIMN, nullptr, qkv2, BQKV, DIMN);

    // fused differential attention -> bufA
    attn_fused<<<dim3(SEQ / 64, BATCH * HEADS), 256, 0, stream>>>(qkv1, qkv2, bufA);

    // out-proj: bufB = bufA @ Wout^T + bout
    gemm_mfma<<<dim3(DIMN / GBN, NROWS / GBM), 256, 0, stream>>>(
        bufA, DIMN, nullptr, Wout, DIMN, bout, bufB, DIMN, DIMN);

    // LayerNorm -> d_out
    ln_kernel<<<NROWS, 256, 0, stream>>>(bufB, lng, lnb, (float*)d_out);
}

// Round 4
// 734.828 us; speedup vs baseline: 2.9282x; 1.5786x over previous
//
#include <hip/hip_runtime.h>
#include <hip/hip_bf16.h>
#include <math.h>

// Problem constants (fixed by the reference)
#define DIMN   1024
#define HEADS  16
#define DHEAD  64
#define BQKV   3072
#define BATCH  4
#define SEQ    1024
#define NROWS  (BATCH * SEQ)     // 4096
#define ATT_SCALE 0.125f         // 1/sqrt(64)
#define LN_EPS 1e-5f

typedef __attribute__((ext_vector_type(8))) short  bf16x8;
typedef __attribute__((ext_vector_type(4))) float  f32x4;
typedef __attribute__((ext_vector_type(4))) unsigned short u16x4;

// fp32 -> bf16 round-to-nearest-even
__device__ __forceinline__ unsigned short f2bf(float f) {
    unsigned u = __float_as_uint(f);
    u += 0x7FFFu + ((u >> 16) & 1u);
    return (unsigned short)(u >> 16);
}

// ---------------------------------------------------------------------------
// Kernel 1: svd_adapt[d] = sigma * sum_r U[d,r] * (sum_j V[r,j])
// ---------------------------------------------------------------------------
__global__ __launch_bounds__(1024) void svd_kernel(
    const float* __restrict__ U, const float* __restrict__ V,
    const float* __restrict__ sigma_p, float* __restrict__ svd)
{
    __shared__ float part[16][4];
    __shared__ float vsum[4];
    const int tid = threadIdx.x;          // 0..1023
    float v0 = V[0 * DIMN + tid];
    float v1 = V[1 * DIMN + tid];
    float v2 = V[2 * DIMN + tid];
    float v3 = V[3 * DIMN + tid];
    #pragma unroll
    for (int off = 32; off > 0; off >>= 1) {
        v0 += __shfl_down(v0, off);
        v1 += __shfl_down(v1, off);
        v2 += __shfl_down(v2, off);
        v3 += __shfl_down(v3, off);
    }
    const int lane = tid & 63, w = tid >> 6;
    if (lane == 0) { part[w][0] = v0; part[w][1] = v1; part[w][2] = v2; part[w][3] = v3; }
    __syncthreads();
    if (tid < 4) {
        float s = 0.f;
        #pragma unroll
        for (int i = 0; i < 16; ++i) s += part[i][tid];
        vsum[tid] = s;
    }
    __syncthreads();
    const float sg = sigma_p[0];
    float acc = U[tid * 4 + 0] * vsum[0] + U[tid * 4 + 1] * vsum[1]
              + U[tid * 4 + 2] * vsum[2] + U[tid * 4 + 3] * vsum[3];
    svd[tid] = sg * acc;
}

// ---------------------------------------------------------------------------
// Kernel 2: bf16-MFMA GEMM  C = (A (+adapt)) @ W^T (+bias), fp32 accum.
//   (unchanged from round 3 — HW-verified fragment layouts)
// ---------------------------------------------------------------------------
#define GBM 128
#define GBN 128
#define GBK 64

__global__ __launch_bounds__(256, 2) void gemm_mfma(
    const float* __restrict__ A, int lda,
    const float* __restrict__ adapt,          // nullable, length K
    const float* __restrict__ W, int ldw,
    const float* __restrict__ bias,           // nullable, length N
    float* __restrict__ C, int ldc, int K)
{
    __shared__ __align__(16) short As[GBM * GBK];   // 16 KB
    __shared__ __align__(16) short Bs[GBN * GBK];   // 16 KB
    const int tid = threadIdx.x;
    const int m0 = blockIdx.y * GBM;
    const int n0 = blockIdx.x * GBN;
    const int lane = tid & 63;
    const int wv = tid >> 6;
    const int wr = wv >> 1, wc = wv & 1;      // wave quadrant
    const int lr = lane & 15;                 // row-in-fragment
    const int kg = lane >> 4;                 // k-group 0..3

    f32x4 acc[4][4];
    #pragma unroll
    for (int i = 0; i < 4; ++i)
        #pragma unroll
        for (int j = 0; j < 4; ++j)
            acc[i][j] = (f32x4){0.f, 0.f, 0.f, 0.f};

    for (int k0 = 0; k0 < K; k0 += GBK) {
        #pragma unroll
        for (int i = 0; i < 8; ++i) {
            int flat = i * 256 + tid;             // 0..2047
            int r  = flat >> 4;                   // row 0..127
            int c4 = flat & 15;                   // float4 index 0..15
            float4 av = *(const float4*)(A + (size_t)(m0 + r) * lda + k0 + c4 * 4);
            if (adapt) {
                float4 sv = *(const float4*)(adapt + k0 + c4 * 4);
                av.x += sv.x; av.y += sv.y; av.z += sv.z; av.w += sv.w;
            }
            u16x4 h;
            h[0] = f2bf(av.x); h[1] = f2bf(av.y); h[2] = f2bf(av.z); h[3] = f2bf(av.w);
            int boff = r * 128 + ((((c4 >> 1) ^ (r & 7)) << 4) | ((c4 & 1) << 3));
            *(u16x4*)((char*)As + boff) = h;
        }
        #pragma unroll
        for (int i = 0; i < 8; ++i) {
            int flat = i * 256 + tid;
            int r  = flat >> 4;
            int c4 = flat & 15;
            float4 wv4 = *(const float4*)(W + (size_t)(n0 + r) * ldw + k0 + c4 * 4);
            u16x4 h;
            h[0] = f2bf(wv4.x); h[1] = f2bf(wv4.y); h[2] = f2bf(wv4.z); h[3] = f2bf(wv4.w);
            int boff = r * 128 + ((((c4 >> 1) ^ (r & 7)) << 4) | ((c4 & 1) << 3));
            *(u16x4*)((char*)Bs + boff) = h;
        }
        __syncthreads();

        #pragma unroll
        for (int ks = 0; ks < 2; ++ks) {
            bf16x8 a[4], b[4];
            #pragma unroll
            for (int mi = 0; mi < 4; ++mi) {
                int row = wr * 64 + mi * 16 + lr;
                int boff = row * 128 + (((ks * 4 + kg) ^ (row & 7)) << 4);
                a[mi] = *(const bf16x8*)((const char*)As + boff);
            }
            #pragma unroll
            for (int ni = 0; ni < 4; ++ni) {
                int row = wc * 64 + ni * 16 + lr;
                int boff = row * 128 + (((ks * 4 + kg) ^ (row & 7)) << 4);
                b[ni] = *(const bf16x8*)((const char*)Bs + boff);
            }
            #pragma unroll
            for (int mi = 0; mi < 4; ++mi)
                #pragma unroll
                for (int ni = 0; ni < 4; ++ni)
                    acc[mi][ni] = __builtin_amdgcn_mfma_f32_16x16x32_bf16(
                        a[mi], b[ni], acc[mi][ni], 0, 0, 0);
        }
        __syncthreads();
    }

    #pragma unroll
    for (int ni = 0; ni < 4; ++ni) {
        const int col = n0 + wc * 64 + ni * 16 + lr;
        const float bs = bias ? bias[col] : 0.f;
        #pragma unroll
        for (int mi = 0; mi < 4; ++mi) {
            const int row = m0 + wr * 64 + mi * 16 + kg * 4;
            #pragma unroll
            for (int r = 0; r < 4; ++r)
                C[(size_t)(row + r) * ldc + col] = acc[mi][ni][r] + bs;
        }
    }
}

// ---------------------------------------------------------------------------
// Kernel 3: MFMA differential flash attention.
//   Block = 4 waves x 16 q-rows = 64 q-rows. Per K-tile of 64 keys:
//     S^T = K·Q^T (swapped: D-layout puts q in lane&15, keys in reg/lane-hi)
//     wave-parallel online softmax (2 shfl_xor per reduce)
//     P bounced via per-wave LDS (2KB) into A-operand layout
//     O += P·V̄ with V̄ staged transposed [dim][key]
//   All LDS tiles XOR-swizzled by ((row&7)<<4) -> conflict-free ds_read_b128.
// ---------------------------------------------------------------------------
__global__ __launch_bounds__(256, 2) void attn_mfma(
    const float* __restrict__ qkv1,
    const float* __restrict__ qkv2,
    float* __restrict__ out)
{
    __shared__ __align__(16) short k1s[64 * 64];       // 8 KB, [key][dim] swz
    __shared__ __align__(16) short k2s[64 * 64];       // 8 KB
    __shared__ __align__(16) short vts[64 * 64];       // 8 KB, [dim][key] swz
    __shared__ __align__(16) short pbufs[4][16 * 64];  // 8 KB, per-wave [q][key] swz

    const int tid = threadIdx.x;
    const int lane = tid & 63;
    const int wv = tid >> 6;
    const int lr = lane & 15;
    const int kg = lane >> 4;
    const int bh = blockIdx.y;
    const int b = bh >> 4, h = bh & 15;
    const int bS = b * SEQ;
    const int q0w = blockIdx.x * 64 + wv * 16;
    short* pw = pbufs[wv];

    // ---- Q fragments (B-operand of swapped QK^T): lane holds
    //      Q[q0w+lr][dims kg*8..+7] per k-step, scaled, bf16 ----
    bf16x8 qf1[2], qf2[2];
    {
        const size_t qrow = (size_t)(bS + q0w + lr) * BQKV + h * DHEAD;
        #pragma unroll
        for (int ks = 0; ks < 2; ++ks) {
            const float* p1 = qkv1 + qrow + ks * 32 + kg * 8;
            float4 a = *(const float4*)p1;
            float4 c = *(const float4*)(p1 + 4);
            bf16x8 f;
            f[0] = (short)f2bf(a.x * ATT_SCALE); f[1] = (short)f2bf(a.y * ATT_SCALE);
            f[2] = (short)f2bf(a.z * ATT_SCALE); f[3] = (short)f2bf(a.w * ATT_SCALE);
            f[4] = (short)f2bf(c.x * ATT_SCALE); f[5] = (short)f2bf(c.y * ATT_SCALE);
            f[6] = (short)f2bf(c.z * ATT_SCALE); f[7] = (short)f2bf(c.w * ATT_SCALE);
            qf1[ks] = f;
            const float* p2 = qkv2 + qrow + ks * 32 + kg * 8;
            a = *(const float4*)p2;
            c = *(const float4*)(p2 + 4);
            f[0] = (short)f2bf(a.x * ATT_SCALE); f[1] = (short)f2bf(a.y * ATT_SCALE);
            f[2] = (short)f2bf(a.z * ATT_SCALE); f[3] = (short)f2bf(a.w * ATT_SCALE);
            f[4] = (short)f2bf(c.x * ATT_SCALE); f[5] = (short)f2bf(c.y * ATT_SCALE);
            f[6] = (short)f2bf(c.z * ATT_SCALE); f[7] = (short)f2bf(c.w * ATT_SCALE);
            qf2[ks] = f;
        }
    }

    f32x4 o1[4], o2[4];
    #pragma unroll
    for (int i = 0; i < 4; ++i) {
        o1[i] = (f32x4){0.f, 0.f, 0.f, 0.f};
        o2[i] = (f32x4){0.f, 0.f, 0.f, 0.f};
    }
    float m1 = -1e30f, l1 = 0.f, m2 = -1e30f, l2 = 0.f;

    for (int kt = 0; kt < SEQ; kt += 64) {
        // ---- stage K1,K2 [64 keys][64 dims] bf16, swizzled ----
        #pragma unroll
        for (int i = 0; i < 4; ++i) {
            int flat = i * 256 + tid;            // 0..1023
            int r  = flat >> 4;                  // key 0..63
            int c4 = flat & 15;                  // float4 idx
            size_t g = (size_t)(bS + kt + r) * BQKV + 1024 + h * DHEAD + c4 * 4;
            int boff = r * 128 + ((((c4 >> 1) ^ (r & 7)) << 4) | ((c4 & 1) << 3));
            float4 a = *(const float4*)(qkv1 + g);
            u16x4 ha;
            ha[0] = f2bf(a.x); ha[1] = f2bf(a.y); ha[2] = f2bf(a.z); ha[3] = f2bf(a.w);
            *(u16x4*)((char*)k1s + boff) = ha;
            float4 c = *(const float4*)(qkv2 + g);
            u16x4 hb;
            hb[0] = f2bf(c.x); hb[1] = f2bf(c.y); hb[2] = f2bf(c.z); hb[3] = f2bf(c.w);
            *(u16x4*)((char*)k2s + boff) = hb;
        }
        // ---- stage V̄^T [64 dims][64 keys] bf16, swizzled ----
        #pragma unroll
        for (int i = 0; i < 2; ++i) {
            int idx = i * 256 + tid;             // 0..511
            int kp = idx & 31;                   // key pair: keys 2kp, 2kp+1
            int dg = idx >> 5;                   // dim group: dims dg*4..+3
            size_t g = (size_t)(bS + kt + 2 * kp) * BQKV + 2048 + h * DHEAD + dg * 4;
            float4 x0 = *(const float4*)(qkv1 + g);
            float4 y0 = *(const float4*)(qkv2 + g);
            float4 x1 = *(const float4*)(qkv1 + g + BQKV);
            float4 y1 = *(const float4*)(qkv2 + g + BQKV);
            float a0 = 0.5f * (x0.x + y0.x), a1 = 0.5f * (x0.y + y0.y);
            float a2 = 0.5f * (x0.z + y0.z), a3 = 0.5f * (x0.w + y0.w);
            float b0 = 0.5f * (x1.x + y1.x), b1 = 0.5f * (x1.y + y1.y);
            float b2 = 0.5f * (x1.z + y1.z), b3 = 0.5f * (x1.w + y1.w);
            float av[4] = {a0, a1, a2, a3};
            float bv[4] = {b0, b1, b2, b3};
            #pragma unroll
            for (int j = 0; j < 4; ++j) {
                unsigned pk = (unsigned)f2bf(av[j]) | ((unsigned)f2bf(bv[j]) << 16);
                int dim = dg * 4 + j;
                int boff = dim * 128 + ((((kp >> 2) ^ (dim & 7)) << 4) | ((kp & 3) << 2));
                *(unsigned*)((char*)vts + boff) = pk;
            }
        }
        __syncthreads();

        // ---- S^T = K·Q^T : 4 key-frags x 2 k-steps per branch ----
        f32x4 s1[4], s2[4];
        #pragma unroll
        for (int f = 0; f < 4; ++f) {
            s1[f] = (f32x4){0.f, 0.f, 0.f, 0.f};
            s2[f] = (f32x4){0.f, 0.f, 0.f, 0.f};
        }
        #pragma unroll
        for (int ks = 0; ks < 2; ++ks) {
            #pragma unroll
            for (int f = 0; f < 4; ++f) {
                int row = f * 16 + lr;           // key row
                int boff = row * 128 + (((ks * 4 + kg) ^ (row & 7)) << 4);
                bf16x8 a1 = *(const bf16x8*)((const char*)k1s + boff);
                bf16x8 a2 = *(const bf16x8*)((const char*)k2s + boff);
                s1[f] = __builtin_amdgcn_mfma_f32_16x16x32_bf16(a1, qf1[ks], s1[f], 0, 0, 0);
                s2[f] = __builtin_amdgcn_mfma_f32_16x16x32_bf16(a2, qf2[ks], s2[f], 0, 0, 0);
            }
        }

        // ---- per-branch online softmax + PV ----
        #pragma unroll
        for (int br = 0; br < 2; ++br) {
            f32x4* sf = br ? s2 : s1;
            float& m = br ? m2 : m1;
            float& l = br ? l2 : l1;
            f32x4* oacc = br ? o2 : o1;

            float tm = -1e30f;
            #pragma unroll
            for (int f = 0; f < 4; ++f)
                #pragma unroll
                for (int r = 0; r < 4; ++r) tm = fmaxf(tm, sf[f][r]);
            tm = fmaxf(tm, __shfl_xor(tm, 16));
            tm = fmaxf(tm, __shfl_xor(tm, 32));
            float mnew = fmaxf(m, tm);
            float sc = __expf(m - mnew);
            m = mnew;

            float psum = 0.f;
            #pragma unroll
            for (int f = 0; f < 4; ++f) {
                u16x4 hw;
                #pragma unroll
                for (int r = 0; r < 4; ++r) {
                    float p = __expf(sf[f][r] - mnew);
                    unsigned short hb = f2bf(p);
                    hw[r] = hb;
                    psum += __uint_as_float((unsigned)hb << 16);  // sum the rounded p
                }
                // write P[q=lr][key=f*16+kg*4+r], swizzled by (q&7)
                int boff = lr * 128 + ((((f * 2 + (kg >> 1)) ^ (lr & 7)) << 4) | ((kg & 1) << 3));
                *(u16x4*)((char*)pw + boff) = hw;
            }
            psum += __shfl_xor(psum, 16);
            psum += __shfl_xor(psum, 32);
            l = l * sc + psum;

            // rescale O (redistribute sc from q=lane&15 domain to q=kg*4+r domain)
            #pragma unroll
            for (int r = 0; r < 4; ++r) {
                float scr = __shfl(sc, (kg << 2) | r);
                #pragma unroll
                for (int nf = 0; nf < 4; ++nf) oacc[nf][r] *= scr;
            }

            // PV: O += P·V̄  (A = P from pbuf, B = V̄ from transposed tile)
            #pragma unroll
            for (int ks = 0; ks < 2; ++ks) {
                int boffp = lr * 128 + (((ks * 4 + kg) ^ (lr & 7)) << 4);
                bf16x8 ap = *(const bf16x8*)((const char*)pw + boffp);
                #pragma unroll
                for (int nf = 0; nf < 4; ++nf) {
                    int dim = nf * 16 + lr;
                    int boffv = dim * 128 + (((ks * 4 + kg) ^ (dim & 7)) << 4);
                    bf16x8 bv = *(const bf16x8*)((const char*)vts + boffv);
                    oacc[nf] = __builtin_amdgcn_mfma_f32_16x16x32_bf16(ap, bv, oacc[nf], 0, 0, 0);
                }
            }
        }
        __syncthreads();
    }

    // ---- epilogue: out = O1/l1 - O2/l2 ----
    const float inv1 = 1.f / l1, inv2 = 1.f / l2;
    #pragma unroll
    for (int r = 0; r < 4; ++r) {
        float r1 = __shfl(inv1, (kg << 2) | r);
        float r2 = __shfl(inv2, (kg << 2) | r);
        float* op = out + (size_t)(bS + q0w + kg * 4 + r) * DIMN + h * DHEAD + lr;
        #pragma unroll
        for (int nf = 0; nf < 4; ++nf)
            op[nf * 16] = o1[nf][r] * r1 - o2[nf][r] * r2;
    }
}

// ---------------------------------------------------------------------------
// Kernel 4: LayerNorm over last dim (1024), one block per row.
// ---------------------------------------------------------------------------
__global__ __launch_bounds__(256) void ln_kernel(
    const float* __restrict__ X, const float* __restrict__ g,
    const float* __restrict__ bi, float* __restrict__ out)
{
    __shared__ float red[8];
    const int row = blockIdx.x;
    const int tid = threadIdx.x;
    const float* xp = X + (size_t)row * DIMN;
    float4 xv = *(const float4*)(xp + tid * 4);
    float s = xv.x + xv.y + xv.z + xv.w;
    #pragma unroll
    for (int off = 32; off > 0; off >>= 1) s += __shfl_down(s, off);
    const int lane = tid & 63, w = tid >> 6;
    if (lane == 0) red[w] = s;
    __syncthreads();
    const float mu = (red[0] + red[1] + red[2] + red[3]) * (1.f / DIMN);
    const float d0 = xv.x - mu, d1 = xv.y - mu, d2 = xv.z - mu, d3 = xv.w - mu;
    float sq = d0 * d0 + d1 * d1 + d2 * d2 + d3 * d3;
    #pragma unroll
    for (int off = 32; off > 0; off >>= 1) sq += __shfl_down(sq, off);
    if (lane == 0) red[4 + w] = sq;
    __syncthreads();
    const float var = (red[4] + red[5] + red[6] + red[7]) * (1.f / DIMN);
    const float inv = rsqrtf(var + LN_EPS);
    float4 gv = *(const float4*)(g + tid * 4);
    float4 bv = *(const float4*)(bi + tid * 4);
    float4 ov;
    ov.x = d0 * inv * gv.x + bv.x;
    ov.y = d1 * inv * gv.y + bv.y;
    ov.z = d2 * inv * gv.z + bv.z;
    ov.w = d3 * inv * gv.w + bv.w;
    *(float4*)(out + (size_t)row * DIMN + tid * 4) = ov;
}

// ---------------------------------------------------------------------------
// Launch. Workspace layout (bytes):
//   [0,4K)          svd_adapt[1024]
//   [4K, +16M)      bufA : x1p, later attn_out
//   [+16M, +16M)    bufB : x2p, later out-proj result
//   [+48M)          qkv1
//   [+48M)          qkv2
// ---------------------------------------------------------------------------
extern "C" void kernel_launch(void* const* d_in, const int* in_sizes, int n_in,
                              void* d_out, int out_size, void* d_ws, size_t ws_size,
                              hipStream_t stream)
{
    const float* x     = (const float*)d_in[0];
    const float* sigma = (const float*)d_in[1];
    const float* U     = (const float*)d_in[2];
    const float* V     = (const float*)d_in[3];
    const float* Wp1   = (const float*)d_in[4];
    const float* bp1   = (const float*)d_in[5];
    const float* Wp2   = (const float*)d_in[6];
    const float* bp2   = (const float*)d_in[7];
    const float* Wqkv1 = (const float*)d_in[8];
    const float* Wqkv2 = (const float*)d_in[9];
    const float* Wout  = (const float*)d_in[10];
    const float* bout  = (const float*)d_in[11];
    const float* lng   = (const float*)d_in[12];
    const float* lnb   = (const float*)d_in[13];

    const size_t ACT = (size_t)NROWS * DIMN * sizeof(float);   // 16 MB
    const size_t QKV = (size_t)NROWS * BQKV * sizeof(float);   // 48 MB
    char* ws = (char*)d_ws;
    float* svd  = (float*)(ws);
    float* bufA = (float*)(ws + 4096);
    float* bufB = (float*)(ws + 4096 + ACT);
    float* qkv1 = (float*)(ws + 4096 + 2 * ACT);
    float* qkv2 = (float*)(ws + 4096 + 2 * ACT + QKV);

    svd_kernel<<<1, 1024, 0, stream>>>(U, V, sigma, svd);

    // x1p = (x[:, :512]+svd[:512]) @ Wp1^T + bp1   -> bufA
    gemm_mfma<<<dim3(DIMN / GBN, NROWS / GBM), 256, 0, stream>>>(
        x, DIMN, svd, Wp1, DIMN / 2, bp1, bufA, DIMN, DIMN / 2);
    // x2p -> bufB
    gemm_mfma<<<dim3(DIMN / GBN, NROWS / GBM), 256, 0, stream>>>(
        x + DIMN / 2, DIMN, svd + DIMN / 2, Wp2, DIMN / 2, bp2, bufB, DIMN, DIMN / 2);
    // qkv1 = x1p @ Wqkv1^T
    gemm_mfma<<<dim3(BQKV / GBN, NROWS / GBM), 256, 0, stream>>>(
        bufA, DIMN, nullptr, Wqkv1, DIMN, nullptr, qkv1, BQKV, DIMN);
    // qkv2 = x2p @ Wqkv2^T
    gemm_mfma<<<dim3(BQKV / GBN, NROWS / GBM), 256, 0, stream>>>(
        bufB, DIMN, nullptr, Wqkv2, DIMN, nullptr, qkv2, BQKV, DIMN);

    // MFMA differential attention -> bufA
    attn_mfma<<<dim3(SEQ / 64, BATCH * HEADS), 256, 0, stream>>>(qkv1, qkv2, bufA);

    // out-proj: bufB = bufA @ Wout^T + bout
    gemm_mfma<<<dim3(DIMN / GBN, NROWS / GBM), 256, 0, stream>>>(
        bufA, DIMN, nullptr, Wout, DIMN, bout, bufB, DIMN, DIMN);

    // LayerNorm -> d_out
    ln_kernel<<<NROWS, 256, 0, stream>>>(bufB, lng, lnb, (float*)d_out);
}

// Round 9
// 367.858 us; speedup vs baseline: 5.8494x; 1.9976x over previous
//
#include <hip/hip_runtime.h>
#include <hip/hip_bf16.h>
#include <math.h>

// Problem constants (fixed by the reference)
#define DIMN   1024
#define HEADS  16
#define DHEAD  64
#define BQKV   3072
#define BATCH  4
#define SEQ    1024
#define NROWS  (BATCH * SEQ)     // 4096
#define ATT_SCALE 0.125f         // 1/sqrt(64), exact power of two
#define LN_EPS 1e-5f

typedef __attribute__((ext_vector_type(8))) short  bf16x8;
typedef __attribute__((ext_vector_type(4))) float  f32x4;
typedef __attribute__((ext_vector_type(4))) unsigned short u16x4;

// fp32 -> bf16 round-to-nearest-even
__device__ __forceinline__ unsigned short f2bf(float f) {
    unsigned u = __float_as_uint(f);
    u += 0x7FFFu + ((u >> 16) & 1u);
    return (unsigned short)(u >> 16);
}
__device__ __forceinline__ float bf2f(unsigned short h) {
    return __uint_as_float((unsigned)h << 16);
}
// async global->LDS 16B copy (wave-uniform dest = base + lane*16)
__device__ __forceinline__ void gload_lds16(const void* g, void* l) {
    __builtin_amdgcn_global_load_lds(
        (const __attribute__((address_space(1))) unsigned int*)g,
        (__attribute__((address_space(3))) unsigned int*)l, 16, 0, 0);
}

// ---------------------------------------------------------------------------
// Kernel 1: svd_adapt[d] = sigma * sum_r U[d,r] * (sum_j V[r,j])
// ---------------------------------------------------------------------------
__global__ __launch_bounds__(1024) void svd_kernel(
    const float* __restrict__ U, const float* __restrict__ V,
    const float* __restrict__ sigma_p, float* __restrict__ svd)
{
    __shared__ float part[16][4];
    __shared__ float vsum[4];
    const int tid = threadIdx.x;          // 0..1023
    float v0 = V[0 * DIMN + tid];
    float v1 = V[1 * DIMN + tid];
    float v2 = V[2 * DIMN + tid];
    float v3 = V[3 * DIMN + tid];
    #pragma unroll
    for (int off = 32; off > 0; off >>= 1) {
        v0 += __shfl_down(v0, off);
        v1 += __shfl_down(v1, off);
        v2 += __shfl_down(v2, off);
        v3 += __shfl_down(v3, off);
    }
    const int lane = tid & 63, w = tid >> 6;
    if (lane == 0) { part[w][0] = v0; part[w][1] = v1; part[w][2] = v2; part[w][3] = v3; }
    __syncthreads();
    if (tid < 4) {
        float s = 0.f;
        #pragma unroll
        for (int i = 0; i < 16; ++i) s += part[i][tid];
        vsum[tid] = s;
    }
    __syncthreads();
    const float sg = sigma_p[0];
    float acc = U[tid * 4 + 0] * vsum[0] + U[tid * 4 + 1] * vsum[1]
              + U[tid * 4 + 2] * vsum[2] + U[tid * 4 + 3] * vsum[3];
    svd[tid] = sg * acc;
}

// ---------------------------------------------------------------------------
// Kernel 1b: fp32 -> bf16 bulk convert (n multiple of 2048)
// ---------------------------------------------------------------------------
__global__ __launch_bounds__(256) void cvt_kernel(
    const float* __restrict__ src, unsigned short* __restrict__ dst)
{
    const int i = (blockIdx.x * 256 + threadIdx.x) * 8;
    float4 a = *(const float4*)(src + i);
    float4 b = *(const float4*)(src + i + 4);
    u16x4 h0, h1;
    h0[0] = f2bf(a.x); h0[1] = f2bf(a.y); h0[2] = f2bf(a.z); h0[3] = f2bf(a.w);
    h1[0] = f2bf(b.x); h1[1] = f2bf(b.y); h1[2] = f2bf(b.z); h1[3] = f2bf(b.w);
    *(u16x4*)(dst + i) = h0;
    *(u16x4*)(dst + i + 4) = h1;
}

// Kernel 1c: xadapt = bf16(x + svd[d])   (4096x1024)
__global__ __launch_bounds__(256) void xadapt_kernel(
    const float* __restrict__ x, const float* __restrict__ svd,
    unsigned short* __restrict__ out)
{
    const int i = (blockIdx.x * 256 + threadIdx.x) * 8;
    const int d = i & (DIMN - 1);
    float4 a = *(const float4*)(x + i);
    float4 b = *(const float4*)(x + i + 4);
    float4 sa = *(const float4*)(svd + d);
    float4 sb = *(const float4*)(svd + d + 4);
    u16x4 h0, h1;
    h0[0] = f2bf(a.x + sa.x); h0[1] = f2bf(a.y + sa.y);
    h0[2] = f2bf(a.z + sa.z); h0[3] = f2bf(a.w + sa.w);
    h1[0] = f2bf(b.x + sb.x); h1[1] = f2bf(b.y + sb.y);
    h1[2] = f2bf(b.z + sb.z); h1[3] = f2bf(b.w + sb.w);
    *(u16x4*)(out + i) = h0;
    *(u16x4*)(out + i + 4) = h1;
}

// ---------------------------------------------------------------------------
// Kernel 2: bf16 MFMA GEMM  C = A @ W^T (+bias), fp32 accum.
//   A: [M,K] bf16 (lda), W: [N,K] bf16 (ldw). Staging via global_load_lds
//   width-16 with PRE-SWIZZLED global source (LDS dest linear); reads use the
//   matching XOR swizzle. out_bf16 selects bf16 or fp32 C.
// ---------------------------------------------------------------------------
#define GBM 128
#define GBN 128
#define GBK 64

__global__ __launch_bounds__(256, 2) void gemm_bf16(
    const unsigned short* __restrict__ A, int lda,
    const unsigned short* __restrict__ W, int ldw,
    const float* __restrict__ bias,           // nullable, length N
    void* __restrict__ C, int ldc, int K, int out_bf16)
{
    __shared__ __align__(16) short As[GBM * GBK];   // 16 KB
    __shared__ __align__(16) short Bs[GBN * GBK];   // 16 KB
    const int tid = threadIdx.x;
    const int m0 = blockIdx.y * GBM;
    const int n0 = blockIdx.x * GBN;
    const int lane = tid & 63;
    const int wv = tid >> 6;
    const int wr = wv >> 1, wc = wv & 1;      // wave quadrant
    const int lr = lane & 15;                 // row-in-fragment
    const int kg = lane >> 4;                 // k-group 0..3

    f32x4 acc[4][4];
    #pragma unroll
    for (int i = 0; i < 4; ++i)
        #pragma unroll
        for (int j = 0; j < 4; ++j)
            acc[i][j] = (f32x4){0.f, 0.f, 0.f, 0.f};

    for (int k0 = 0; k0 < K; k0 += GBK) {
        // stage A,B: 1024 16B-chunks each; physical slot c of row r holds
        // logical chunk c^(r&7)  ->  source addr uses sc = c^(r&7)
        #pragma unroll
        for (int i = 0; i < 4; ++i) {
            int flat = i * 256 + tid;             // 0..1023
            int r = flat >> 3, c = flat & 7;
            int sc = c ^ (r & 7);
            gload_lds16(A + (size_t)(m0 + r) * lda + k0 + sc * 8, As + flat * 8);
        }
        #pragma unroll
        for (int i = 0; i < 4; ++i) {
            int flat = i * 256 + tid;
            int r = flat >> 3, c = flat & 7;
            int sc = c ^ (r & 7);
            gload_lds16(W + (size_t)(n0 + r) * ldw + k0 + sc * 8, Bs + flat * 8);
        }
        __syncthreads();

        #pragma unroll
        for (int ks = 0; ks < 2; ++ks) {
            bf16x8 a[4], b[4];
            #pragma unroll
            for (int mi = 0; mi < 4; ++mi) {
                int row = wr * 64 + mi * 16 + lr;
                int boff = row * 128 + (((ks * 4 + kg) ^ (row & 7)) << 4);
                a[mi] = *(const bf16x8*)((const char*)As + boff);
            }
            #pragma unroll
            for (int ni = 0; ni < 4; ++ni) {
                int row = wc * 64 + ni * 16 + lr;
                int boff = row * 128 + (((ks * 4 + kg) ^ (row & 7)) << 4);
                b[ni] = *(const bf16x8*)((const char*)Bs + boff);
            }
            #pragma unroll
            for (int mi = 0; mi < 4; ++mi)
                #pragma unroll
                for (int ni = 0; ni < 4; ++ni)
                    acc[mi][ni] = __builtin_amdgcn_mfma_f32_16x16x32_bf16(
                        a[mi], b[ni], acc[mi][ni], 0, 0, 0);
        }
        __syncthreads();
    }

    // C write: D row = kg*4 + reg, col = lr (HW-verified layout)
    #pragma unroll
    for (int ni = 0; ni < 4; ++ni) {
        const int col = n0 + wc * 64 + ni * 16 + lr;
        const float bs = bias ? bias[col] : 0.f;
        #pragma unroll
        for (int mi = 0; mi < 4; ++mi) {
            const int row = m0 + wr * 64 + mi * 16 + kg * 4;
            #pragma unroll
            for (int r = 0; r < 4; ++r) {
                float v = acc[mi][ni][r] + bs;
                if (out_bf16)
                    ((unsigned short*)C)[(size_t)(row + r) * ldc + col] = f2bf(v);
                else
                    ((float*)C)[(size_t)(row + r) * ldc + col] = v;
            }
        }
    }
}

// ---------------------------------------------------------------------------
// Kernel 3: MFMA differential flash attention (bf16 qkv in, bf16 out).
//   Block = 4 waves x 16 q-rows. S^T = K·Q^T (q in lane&15), wave-parallel
//   online softmax, P via per-wave LDS, O += P·V̄ with V̄^T staged [dim][key].
//   K tiles staged with global_load_lds (pre-swizzled source).
// ---------------------------------------------------------------------------
__global__ __launch_bounds__(256, 2) void attn_mfma(
    const unsigned short* __restrict__ qkv1,
    const unsigned short* __restrict__ qkv2,
    unsigned short* __restrict__ out)
{
    __shared__ __align__(16) short k1s[64 * 64];       // 8 KB, [key][dim] swz
    __shared__ __align__(16) short k2s[64 * 64];       // 8 KB
    __shared__ __align__(16) short vts[64 * 64];       // 8 KB, [dim][key] swz
    __shared__ __align__(16) short pbufs[4][16 * 64];  // 8 KB, per-wave [q][key] swz

    const int tid = threadIdx.x;
    const int lane = tid & 63;
    const int wv = tid >> 6;
    const int lr = lane & 15;
    const int kg = lane >> 4;
    const int bh = blockIdx.y;
    const int b = bh >> 4, h = bh & 15;
    const int bS = b * SEQ;
    const int q0w = blockIdx.x * 64 + wv * 16;
    short* pw = pbufs[wv];

    // ---- Q fragments: lane holds Q[q0w+lr][kg*8..+7] per k-step, scaled ----
    bf16x8 qf1[2], qf2[2];
    {
        const size_t qrow = (size_t)(bS + q0w + lr) * BQKV + h * DHEAD;
        #pragma unroll
        for (int ks = 0; ks < 2; ++ks) {
            const unsigned short* p1 = qkv1 + qrow + ks * 32 + kg * 8;
            const unsigned short* p2 = qkv2 + qrow + ks * 32 + kg * 8;
            bf16x8 f;
            #pragma unroll
            for (int j = 0; j < 8; ++j) f[j] = (short)f2bf(bf2f(p1[j]) * ATT_SCALE);
            qf1[ks] = f;
            #pragma unroll
            for (int j = 0; j < 8; ++j) f[j] = (short)f2bf(bf2f(p2[j]) * ATT_SCALE);
            qf2[ks] = f;
        }
    }

    f32x4 o1[4], o2[4];
    #pragma unroll
    for (int i = 0; i < 4; ++i) {
        o1[i] = (f32x4){0.f, 0.f, 0.f, 0.f};
        o2[i] = (f32x4){0.f, 0.f, 0.f, 0.f};
    }
    float m1 = -1e30f, l1 = 0.f, m2 = -1e30f, l2 = 0.f;

    for (int kt = 0; kt < SEQ; kt += 64) {
        // ---- stage K1,K2 via global_load_lds, pre-swizzled source ----
        #pragma unroll
        for (int i = 0; i < 2; ++i) {
            int flat = i * 256 + tid;            // 0..511
            int r = flat >> 3, c = flat & 7;
            int sc = c ^ (r & 7);
            size_t g = (size_t)(bS + kt + r) * BQKV + 1024 + h * DHEAD + sc * 8;
            gload_lds16(qkv1 + g, k1s + flat * 8);
            gload_lds16(qkv2 + g, k2s + flat * 8);
        }
        // ---- stage V̄^T [64 dims][64 keys] bf16, swizzled (reg path) ----
        #pragma unroll
        for (int i = 0; i < 2; ++i) {
            int idx = i * 256 + tid;             // 0..511
            int kp = idx & 31;                   // keys 2kp, 2kp+1
            int dg = idx >> 5;                   // dims dg*4..+3
            size_t g = (size_t)(bS + kt + 2 * kp) * BQKV + 2048 + h * DHEAD + dg * 4;
            u16x4 x0 = *(const u16x4*)(qkv1 + g);
            u16x4 y0 = *(const u16x4*)(qkv2 + g);
            u16x4 x1 = *(const u16x4*)(qkv1 + g + BQKV);
            u16x4 y1 = *(const u16x4*)(qkv2 + g + BQKV);
            #pragma unroll
            for (int j = 0; j < 4; ++j) {
                float a = 0.5f * (bf2f(x0[j]) + bf2f(y0[j]));
                float c = 0.5f * (bf2f(x1[j]) + bf2f(y1[j]));
                unsigned pk = (unsigned)f2bf(a) | ((unsigned)f2bf(c) << 16);
                int dim = dg * 4 + j;
                int boff = dim * 128 + ((((kp >> 2) ^ (dim & 7)) << 4) | ((kp & 3) << 2));
                *(unsigned*)((char*)vts + boff) = pk;
            }
        }
        __syncthreads();

        // ---- S^T = K·Q^T ----
        f32x4 s1[4], s2[4];
        #pragma unroll
        for (int f = 0; f < 4; ++f) {
            s1[f] = (f32x4){0.f, 0.f, 0.f, 0.f};
            s2[f] = (f32x4){0.f, 0.f, 0.f, 0.f};
        }
        #pragma unroll
        for (int ks = 0; ks < 2; ++ks) {
            #pragma unroll
            for (int f = 0; f < 4; ++f) {
                int row = f * 16 + lr;           // key row
                int boff = row * 128 + (((ks * 4 + kg) ^ (row & 7)) << 4);
                bf16x8 a1 = *(const bf16x8*)((const char*)k1s + boff);
                bf16x8 a2 = *(const bf16x8*)((const char*)k2s + boff);
                s1[f] = __builtin_amdgcn_mfma_f32_16x16x32_bf16(a1, qf1[ks], s1[f], 0, 0, 0);
                s2[f] = __builtin_amdgcn_mfma_f32_16x16x32_bf16(a2, qf2[ks], s2[f], 0, 0, 0);
            }
        }

        // ---- per-branch online softmax + PV ----
        #pragma unroll
        for (int br = 0; br < 2; ++br) {
            f32x4* sf = br ? s2 : s1;
            float& m = br ? m2 : m1;
            float& l = br ? l2 : l1;
            f32x4* oacc = br ? o2 : o1;

            float tm = -1e30f;
            #pragma unroll
            for (int f = 0; f < 4; ++f)
                #pragma unroll
                for (int r = 0; r < 4; ++r) tm = fmaxf(tm, sf[f][r]);
            tm = fmaxf(tm, __shfl_xor(tm, 16));
            tm = fmaxf(tm, __shfl_xor(tm, 32));
            float mnew = fmaxf(m, tm);
            float sc = __expf(m - mnew);
            m = mnew;

            float psum = 0.f;
            #pragma unroll
            for (int f = 0; f < 4; ++f) {
                u16x4 hw;
                #pragma unroll
                for (int r = 0; r < 4; ++r) {
                    float p = __expf(sf[f][r] - mnew);
                    unsigned short hb = f2bf(p);
                    hw[r] = hb;
                    psum += bf2f(hb);            // sum the rounded p
                }
                int boff = lr * 128 + ((((f * 2 + (kg >> 1)) ^ (lr & 7)) << 4) | ((kg & 1) << 3));
                *(u16x4*)((char*)pw + boff) = hw;
            }
            psum += __shfl_xor(psum, 16);
            psum += __shfl_xor(psum, 32);
            l = l * sc + psum;

            #pragma unroll
            for (int r = 0; r < 4; ++r) {
                float scr = __shfl(sc, (kg << 2) | r);
                #pragma unroll
                for (int nf = 0; nf < 4; ++nf) oacc[nf][r] *= scr;
            }

            #pragma unroll
            for (int ks = 0; ks < 2; ++ks) {
                int boffp = lr * 128 + (((ks * 4 + kg) ^ (lr & 7)) << 4);
                bf16x8 ap = *(const bf16x8*)((const char*)pw + boffp);
                #pragma unroll
                for (int nf = 0; nf < 4; ++nf) {
                    int dim = nf * 16 + lr;
                    int boffv = dim * 128 + (((ks * 4 + kg) ^ (dim & 7)) << 4);
                    bf16x8 bv = *(const bf16x8*)((const char*)vts + boffv);
                    oacc[nf] = __builtin_amdgcn_mfma_f32_16x16x32_bf16(ap, bv, oacc[nf], 0, 0, 0);
                }
            }
        }
        __syncthreads();
    }

    // ---- epilogue: out = bf16(O1/l1 - O2/l2) ----
    const float inv1 = 1.f / l1, inv2 = 1.f / l2;
    #pragma unroll
    for (int r = 0; r < 4; ++r) {
        float r1 = __shfl(inv1, (kg << 2) | r);
        float r2 = __shfl(inv2, (kg << 2) | r);
        unsigned short* op = out + (size_t)(bS + q0w + kg * 4 + r) * DIMN + h * DHEAD + lr;
        #pragma unroll
        for (int nf = 0; nf < 4; ++nf)
            op[nf * 16] = f2bf(o1[nf][r] * r1 - o2[nf][r] * r2);
    }
}

// ---------------------------------------------------------------------------
// Kernel 4: LayerNorm over last dim (1024), one block per row.
// ---------------------------------------------------------------------------
__global__ __launch_bounds__(256) void ln_kernel(
    const float* __restrict__ X, const float* __restrict__ g,
    const float* __restrict__ bi, float* __restrict__ out)
{
    __shared__ float red[8];
    const int row = blockIdx.x;
    const int tid = threadIdx.x;
    const float* xp = X + (size_t)row * DIMN;
    float4 xv = *(const float4*)(xp + tid * 4);
    float s = xv.x + xv.y + xv.z + xv.w;
    #pragma unroll
    for (int off = 32; off > 0; off >>= 1) s += __shfl_down(s, off);
    const int lane = tid & 63, w = tid >> 6;
    if (lane == 0) red[w] = s;
    __syncthreads();
    const float mu = (red[0] + red[1] + red[2] + red[3]) * (1.f / DIMN);
    const float d0 = xv.x - mu, d1 = xv.y - mu, d2 = xv.z - mu, d3 = xv.w - mu;
    float sq = d0 * d0 + d1 * d1 + d2 * d2 + d3 * d3;
    #pragma unroll
    for (int off = 32; off > 0; off >>= 1) sq += __shfl_down(sq, off);
    if (lane == 0) red[4 + w] = sq;
    __syncthreads();
    const float var = (red[4] + red[5] + red[6] + red[7]) * (1.f / DIMN);
    const float inv = rsqrtf(var + LN_EPS);
    float4 gv = *(const float4*)(g + tid * 4);
    float4 bv = *(const float4*)(bi + tid * 4);
    float4 ov;
    ov.x = d0 * inv * gv.x + bv.x;
    ov.y = d1 * inv * gv.y + bv.y;
    ov.z = d2 * inv * gv.z + bv.z;
    ov.w = d3 * inv * gv.w + bv.w;
    *(float4*)(out + (size_t)row * DIMN + tid * 4) = ov;
}

// ---------------------------------------------------------------------------
// Launch. Workspace (bytes, all 4K-aligned):
//   svd 4K | wp1b 1M | wp2b 1M | wq1b 6M | wq2b 6M | woutb 2M
//   xadapt 8M | x1p 8M | x2p 8M | qkv1b 24M | qkv2b 24M | attno 8M | bufO 16M
// ---------------------------------------------------------------------------
extern "C" void kernel_launch(void* const* d_in, const int* in_sizes, int n_in,
                              void* d_out, int out_size, void* d_ws, size_t ws_size,
                              hipStream_t stream)
{
    const float* x     = (const float*)d_in[0];
    const float* sigma = (const float*)d_in[1];
    const float* U     = (const float*)d_in[2];
    const float* V     = (const float*)d_in[3];
    const float* Wp1   = (const float*)d_in[4];
    const float* bp1   = (const float*)d_in[5];
    const float* Wp2   = (const float*)d_in[6];
    const float* bp2   = (const float*)d_in[7];
    const float* Wqkv1 = (const float*)d_in[8];
    const float* Wqkv2 = (const float*)d_in[9];
    const float* Wout  = (const float*)d_in[10];
    const float* bout  = (const float*)d_in[11];
    const float* lng   = (const float*)d_in[12];
    const float* lnb   = (const float*)d_in[13];

    const size_t MB = 1024 * 1024;
    char* ws = (char*)d_ws;
    float*          svd    = (float*)(ws);
    unsigned short* wp1b   = (unsigned short*)(ws + 4096);
    unsigned short* wp2b   = (unsigned short*)(ws + 4096 + 1 * MB);
    unsigned short* wq1b   = (unsigned short*)(ws + 4096 + 2 * MB);
    unsigned short* wq2b   = (unsigned short*)(ws + 4096 + 8 * MB);
    unsigned short* woutb  = (unsigned short*)(ws + 4096 + 14 * MB);
    unsigned short* xadapt = (unsigned short*)(ws + 4096 + 16 * MB);
    unsigned short* x1p    = (unsigned short*)(ws + 4096 + 24 * MB);
    unsigned short* x2p    = (unsigned short*)(ws + 4096 + 32 * MB);
    unsigned short* qkv1b  = (unsigned short*)(ws + 4096 + 40 * MB);
    unsigned short* qkv2b  = (unsigned short*)(ws + 4096 + 64 * MB);
    unsigned short* attno  = (unsigned short*)(ws + 4096 + 88 * MB);
    float*          bufO   = (float*)(ws + 4096 + 96 * MB);

    svd_kernel<<<1, 1024, 0, stream>>>(U, V, sigma, svd);

    // weight conversions (fp32 -> bf16), grid = n/2048
    cvt_kernel<<<256,  256, 0, stream>>>(Wp1,   wp1b);    // 1024*512
    cvt_kernel<<<256,  256, 0, stream>>>(Wp2,   wp2b);
    cvt_kernel<<<1536, 256, 0, stream>>>(Wqkv1, wq1b);    // 3072*1024
    cvt_kernel<<<1536, 256, 0, stream>>>(Wqkv2, wq2b);
    cvt_kernel<<<512,  256, 0, stream>>>(Wout,  woutb);   // 1024*1024
    xadapt_kernel<<<2048, 256, 0, stream>>>(x, svd, xadapt);

    // proj GEMMs: x1p = xadapt[:, :512] @ Wp1^T + bp1 (bf16 out)
    gemm_bf16<<<dim3(DIMN / GBN, NROWS / GBM), 256, 0, stream>>>(
        xadapt, DIMN, wp1b, DIMN / 2, bp1, x1p, DIMN, DIMN / 2, 1);
    gemm_bf16<<<dim3(DIMN / GBN, NROWS / GBM), 256, 0, stream>>>(
        xadapt + DIMN / 2, DIMN, wp2b, DIMN / 2, bp2, x2p, DIMN, DIMN / 2, 1);
    // qkv GEMMs (bf16 out)
    gemm_bf16<<<dim3(BQKV / GBN, NROWS / GBM), 256, 0, stream>>>(
        x1p, DIMN, wq1b, DIMN, nullptr, qkv1b, BQKV, DIMN, 1);
    gemm_bf16<<<dim3(BQKV / GBN, NROWS / GBM), 256, 0, stream>>>(
        x2p, DIMN, wq2b, DIMN, nullptr, qkv2b, BQKV, DIMN, 1);

    // MFMA differential attention -> attno (bf16)
    attn_mfma<<<dim3(SEQ / 64, BATCH * HEADS), 256, 0, stream>>>(qkv1b, qkv2b, attno);

    // out-proj: bufO = attno @ Wout^T + bout (fp32 out)
    gemm_bf16<<<dim3(DIMN / GBN, NROWS / GBM), 256, 0, stream>>>(
        attno, DIMN, woutb, DIMN, bout, bufO, DIMN, DIMN, 0);

    // LayerNorm -> d_out
    ln_kernel<<<NROWS, 256, 0, stream>>>(bufO, lng, lnb, (float*)d_out);
}